// Round 1
// baseline (2097.486 us; speedup 1.0000x reference)
//
#include <hip/hip_runtime.h>
#include <hip/hip_bf16.h>

#define N_NODES 100000
#define E_EDGES 1600000
#define F_IN    10
#define H       64
#define B_GR    128
#define C_CLS   3
#define BN_EPS  1e-5f
#define NH      (N_NODES * H)

// ---------------------------------------------------------------- degree
__global__ void deg_kernel(const int* __restrict__ dst, float* __restrict__ deg) {
    int e = blockIdx.x * blockDim.x + threadIdx.x;
    if (e < E_EDGES) atomicAdd(&deg[dst[e]], 1.0f);
}

__global__ void dinv_kernel(float* __restrict__ deg) {
    int n = blockIdx.x * blockDim.x + threadIdx.x;
    if (n < N_NODES) deg[n] = rsqrtf(deg[n] + 1.0f);   // in-place: deg -> dinv
}

// ---------------------------------------------------------------- dense h @ W
// One wave (64 lanes) per row; 4 rows per 256-thread block. W staged in LDS.
// Row loaded coalesced (lane k holds h[row,k]); __shfl broadcasts h[row,k].
template <int K>
__global__ void matmul_kernel(const float* __restrict__ hin,
                              const float* __restrict__ W,
                              float* __restrict__ hout) {
    __shared__ float Wlds[K * H];
    int tid = threadIdx.x;
    for (int i = tid; i < K * H; i += 256) Wlds[i] = W[i];
    __syncthreads();

    int row  = blockIdx.x * 4 + (tid >> 6);
    int lane = tid & 63;
    if (row >= N_NODES) return;

    float hval = (lane < K) ? hin[row * K + lane] : 0.0f;
    float acc = 0.0f;
#pragma unroll
    for (int k = 0; k < K; ++k)
        acc += __shfl(hval, k) * Wlds[k * H + lane];
    hout[row * H + lane] = acc;
}

// ---------------------------------------------------------------- edge scatter
// One wave per edge: lane i handles feature column i.
__global__ void edge_agg_kernel(const int* __restrict__ src, const int* __restrict__ dst,
                                const float* __restrict__ dinv,
                                const float* __restrict__ hW,
                                float* __restrict__ agg) {
    long long idx = (long long)blockIdx.x * blockDim.x + threadIdx.x;
    int e    = (int)(idx >> 6);
    int lane = (int)(idx & 63);
    if (e >= E_EDGES) return;
    int s = src[e], d = dst[e];
    float coef = dinv[s] * dinv[d];
    atomicAdd(&agg[d * H + lane], hW[s * H + lane] * coef);
}

// ---------------------------------------------------------------- BN + bias + relu
__global__ void finish_kernel(const float* __restrict__ agg, const float* __restrict__ hW,
                              const float* __restrict__ dinv,
                              const float* __restrict__ b,  const float* __restrict__ g,
                              const float* __restrict__ be, const float* __restrict__ m,
                              const float* __restrict__ v,
                              float* __restrict__ hout) {
    int idx = blockIdx.x * blockDim.x + threadIdx.x;
    if (idx >= NH) return;
    int n = idx >> 6, c = idx & 63;
    float scale = g[c] * rsqrtf(v[c] + BN_EPS);
    float shift = be[c] + (b[c] - m[c]) * scale;
    float di = dinv[n];
    float val = (agg[idx] + hW[idx] * di * di) * scale + shift;
    hout[idx] = fmaxf(val, 0.0f);
}

// ---------------------------------------------------------------- mean pool
__global__ void pool_kernel(const float* __restrict__ h, const int* __restrict__ batch,
                            float* __restrict__ pooled, float* __restrict__ counts) {
    long long idx = (long long)blockIdx.x * blockDim.x + threadIdx.x;
    int n    = (int)(idx >> 6);
    int lane = (int)(idx & 63);
    if (n >= N_NODES) return;
    int b = batch[n];
    atomicAdd(&pooled[b * H + lane], h[n * H + lane]);
    if (lane == 0) atomicAdd(&counts[b], 1.0f);
}

// ---------------------------------------------------------------- final MLP
__global__ void mlp_kernel(const float* __restrict__ pooled, const float* __restrict__ counts,
                           const float* __restrict__ fw1, const float* __restrict__ fb1,
                           const float* __restrict__ fw2, const float* __restrict__ fb2,
                           float* __restrict__ out) {
    __shared__ float prow[H];
    __shared__ float hid[H / 2];
    int b = blockIdx.x;
    int t = threadIdx.x;
    float cnt = fmaxf(counts[b], 1.0f);
    prow[t] = pooled[b * H + t] / cnt;
    __syncthreads();
    if (t < H / 2) {
        float acc = fb1[t];
#pragma unroll
        for (int k = 0; k < H; ++k) acc += prow[k] * fw1[k * (H / 2) + t];
        hid[t] = fmaxf(acc, 0.0f);
    }
    __syncthreads();
    if (t < C_CLS) {
        float acc = fb2[t];
#pragma unroll
        for (int j = 0; j < H / 2; ++j) acc += hid[j] * fw2[j * C_CLS + t];
        out[b * C_CLS + t] = acc;
    }
}

// ================================================================ launch
extern "C" void kernel_launch(void* const* d_in, const int* in_sizes, int n_in,
                              void* d_out, int out_size, void* d_ws, size_t ws_size,
                              hipStream_t stream) {
    const float* x          = (const float*)d_in[0];
    const int*   edge_index = (const int*)d_in[1];
    const int*   batch      = (const int*)d_in[2];

    const float* W1 = (const float*)d_in[3];
    const float* b1 = (const float*)d_in[4];
    const float* g1 = (const float*)d_in[5];
    const float* be1= (const float*)d_in[6];
    const float* m1 = (const float*)d_in[7];
    const float* v1 = (const float*)d_in[8];
    const float* W2 = (const float*)d_in[9];
    const float* b2 = (const float*)d_in[10];
    const float* g2 = (const float*)d_in[11];
    const float* be2= (const float*)d_in[12];
    const float* m2 = (const float*)d_in[13];
    const float* v2 = (const float*)d_in[14];
    const float* W3 = (const float*)d_in[15];
    const float* b3 = (const float*)d_in[16];
    const float* g3 = (const float*)d_in[17];
    const float* be3= (const float*)d_in[18];
    const float* m3 = (const float*)d_in[19];
    const float* v3 = (const float*)d_in[20];
    const float* fw1= (const float*)d_in[21];
    const float* fb1= (const float*)d_in[22];
    const float* fw2= (const float*)d_in[23];
    const float* fb2= (const float*)d_in[24];

    const int* src = edge_index;            // edge_index[0, :]
    const int* dst = edge_index + E_EDGES;  // edge_index[1, :]

    float* ws     = (float*)d_ws;
    float* hW     = ws;                 // N*H
    float* agg    = ws + NH;            // N*H
    float* hbuf   = ws + 2 * (size_t)NH;// N*H
    float* deg    = ws + 3 * (size_t)NH;// N  (becomes dinv in-place)
    float* pooled = deg + N_NODES;      // B*H
    float* counts = pooled + B_GR * H;  // B

    float* out = (float*)d_out;

    // degree / dinv
    hipMemsetAsync(deg, 0, N_NODES * sizeof(float), stream);
    hipMemsetAsync(pooled, 0, (B_GR * H + B_GR) * sizeof(float), stream);
    deg_kernel<<<(E_EDGES + 255) / 256, 256, 0, stream>>>(dst, deg);
    dinv_kernel<<<(N_NODES + 255) / 256, 256, 0, stream>>>(deg);

    const int mmGrid   = (N_NODES + 3) / 4;
    const int edgeGrid = (int)(((long long)E_EDGES * 64 + 255) / 256);
    const int ewGrid   = (NH + 255) / 256;

    // ---- layer 1 (K = F_IN)
    matmul_kernel<F_IN><<<mmGrid, 256, 0, stream>>>(x, W1, hW);
    hipMemsetAsync(agg, 0, (size_t)NH * sizeof(float), stream);
    edge_agg_kernel<<<edgeGrid, 256, 0, stream>>>(src, dst, deg, hW, agg);
    finish_kernel<<<ewGrid, 256, 0, stream>>>(agg, hW, deg, b1, g1, be1, m1, v1, hbuf);

    // ---- layer 2
    matmul_kernel<H><<<mmGrid, 256, 0, stream>>>(hbuf, W2, hW);
    hipMemsetAsync(agg, 0, (size_t)NH * sizeof(float), stream);
    edge_agg_kernel<<<edgeGrid, 256, 0, stream>>>(src, dst, deg, hW, agg);
    finish_kernel<<<ewGrid, 256, 0, stream>>>(agg, hW, deg, b2, g2, be2, m2, v2, hbuf);

    // ---- layer 3
    matmul_kernel<H><<<mmGrid, 256, 0, stream>>>(hbuf, W3, hW);
    hipMemsetAsync(agg, 0, (size_t)NH * sizeof(float), stream);
    edge_agg_kernel<<<edgeGrid, 256, 0, stream>>>(src, dst, deg, hW, agg);
    finish_kernel<<<ewGrid, 256, 0, stream>>>(agg, hW, deg, b3, g3, be3, m3, v3, hbuf);

    // ---- pool + MLP head
    pool_kernel<<<(int)(((long long)N_NODES * 64 + 255) / 256), 256, 0, stream>>>(
        hbuf, batch, pooled, counts);
    mlp_kernel<<<B_GR, 64, 0, stream>>>(pooled, counts, fw1, fb1, fw2, fb2, out);
}

// Round 5
// 605.116 us; speedup vs baseline: 3.4663x; 3.4663x over previous
//
#include <hip/hip_runtime.h>
#include <hip/hip_bf16.h>

#define N_NODES 100000
#define E_EDGES 1600000
#define F_IN    10
#define H       64
#define B_GR    128
#define C_CLS   3
#define BN_EPS  1e-5f
#define NH      (N_NODES * H)
#define NBLK_SCAN ((N_NODES + 255) / 256)   // 391

// ---------------------------------------------------------------- degree (int)
__global__ void deg_kernel(const int* __restrict__ dst, int* __restrict__ deg) {
    int e = blockIdx.x * blockDim.x + threadIdx.x;
    if (e < E_EDGES) atomicAdd(&deg[dst[e]], 1);
}

__global__ void dinv_kernel(const int* __restrict__ deg, float* __restrict__ dinv) {
    int n = blockIdx.x * blockDim.x + threadIdx.x;
    if (n < N_NODES) dinv[n] = rsqrtf((float)deg[n] + 1.0f);
}

// ---------------------------------------------------------------- scan (CSR rowptr)
// pass 1: per-block exclusive scan of deg -> rowptr (partial), block totals.
__global__ void scan1_kernel(const int* __restrict__ deg, int* __restrict__ rowptr,
                             int* __restrict__ blockSums) {
    __shared__ int lds[256];
    int t = threadIdx.x;
    int i = blockIdx.x * 256 + t;
    int v = (i < N_NODES) ? deg[i] : 0;
    lds[t] = v;
    __syncthreads();
    for (int off = 1; off < 256; off <<= 1) {
        int add = (t >= off) ? lds[t - off] : 0;
        __syncthreads();
        lds[t] += add;
        __syncthreads();
    }
    if (i < N_NODES) rowptr[i] = lds[t] - v;          // exclusive within block
    if (t == 255) blockSums[blockIdx.x] = lds[255];
}

// pass 2: single block scans the 391 block sums -> exclusive block offsets.
__global__ void scan2_kernel(const int* __restrict__ blockSums, int* __restrict__ blockOff) {
    __shared__ int lds[512];
    int t = threadIdx.x;
    int v = (t < NBLK_SCAN) ? blockSums[t] : 0;
    lds[t] = v;
    __syncthreads();
    for (int off = 1; off < 512; off <<= 1) {
        int add = (t >= off) ? lds[t - off] : 0;
        __syncthreads();
        lds[t] += add;
        __syncthreads();
    }
    if (t < NBLK_SCAN) blockOff[t] = lds[t] - v;       // exclusive
}

// pass 3: add block offsets, emit rowptr[N]=E, init cursor = rowptr.
__global__ void scan3_kernel(int* __restrict__ rowptr, const int* __restrict__ blockOff,
                             int* __restrict__ cursor) {
    int i = blockIdx.x * blockDim.x + threadIdx.x;
    if (i < N_NODES) {
        int r = rowptr[i] + blockOff[i >> 8];
        rowptr[i] = r;
        cursor[i] = r;
    } else if (i == N_NODES) {
        rowptr[N_NODES] = E_EDGES;
    }
}

// ---------------------------------------------------------------- CSR scatter
// edata[slot] = (src_as_float_bits, dinv[src]*dinv[dst])
__global__ void scatter_kernel(const int* __restrict__ src, const int* __restrict__ dst,
                               const float* __restrict__ dinv,
                               int* __restrict__ cursor, float2* __restrict__ edata) {
    int e = blockIdx.x * blockDim.x + threadIdx.x;
    if (e >= E_EDGES) return;
    int s = src[e], d = dst[e];
    int slot = atomicAdd(&cursor[d], 1);
    edata[slot] = make_float2(__int_as_float(s), dinv[s] * dinv[d]);
}

// ---------------------------------------------------------------- dense h @ W
// 16 rows per 256-thread block; thread computes 4 cols via float4.
template <int K>
__global__ __launch_bounds__(256) void matmul_kernel(const float* __restrict__ hin,
                                                     const float* __restrict__ W,
                                                     float* __restrict__ hout) {
    constexpr int KP = (K == 64) ? 65 : (K + 1);
    __shared__ float rowLds[16 * KP];
    __shared__ float Wlds[K * 68];
    int tid  = threadIdx.x;
    int base = blockIdx.x * 16;

    for (int i = tid; i < K * 64; i += 256)
        Wlds[(i >> 6) * 68 + (i & 63)] = W[i];
    for (int i = tid; i < 16 * K; i += 256) {
        int r = i / K, k = i - r * K;
        rowLds[r * KP + k] = hin[(base + r) * K + k];
    }
    __syncthreads();

    int r  = tid >> 4;
    int c4 = (tid & 15) * 4;
    float4 acc = make_float4(0.f, 0.f, 0.f, 0.f);
#pragma unroll
    for (int k = 0; k < K; ++k) {
        float  rv = rowLds[r * KP + k];
        float4 wv = *(const float4*)&Wlds[k * 68 + c4];
        acc.x = fmaf(rv, wv.x, acc.x);
        acc.y = fmaf(rv, wv.y, acc.y);
        acc.z = fmaf(rv, wv.z, acc.z);
        acc.w = fmaf(rv, wv.w, acc.w);
    }
    *(float4*)&hout[(base + r) * H + c4] = acc;
}

// ---------------------------------------------------------------- CSR gather + self + BN + ReLU
// One wave per node; 4 lane-groups of 16 process 4 edges/iter with float4 cols.
__global__ __launch_bounds__(256) void gather_kernel(const int* __restrict__ rowptr,
                                                     const float2* __restrict__ edata,
                                                     const float* __restrict__ hW,
                                                     const float* __restrict__ dinv,
                                                     const float* __restrict__ b,
                                                     const float* __restrict__ g,
                                                     const float* __restrict__ be,
                                                     const float* __restrict__ m,
                                                     const float* __restrict__ v,
                                                     float* __restrict__ hout) {
    int tid  = threadIdx.x;
    int n    = blockIdx.x * 4 + (tid >> 6);
    if (n >= N_NODES) return;
    int lane = tid & 63;
    int grp  = lane >> 4;          // 0..3: which edge in the 4-pack
    int c4   = (lane & 15) * 4;    // feature column base

    int start = rowptr[n], end = rowptr[n + 1];
    float4 acc = make_float4(0.f, 0.f, 0.f, 0.f);
    for (int p = start; p < end; p += 4) {
        int q = p + grp;
        float2 ed = (q < end) ? edata[q] : make_float2(__int_as_float(0), 0.0f);
        int   s = __float_as_int(ed.x);
        float w = ed.y;
        float4 hv = *(const float4*)&hW[s * H + c4];
        acc.x = fmaf(w, hv.x, acc.x);
        acc.y = fmaf(w, hv.y, acc.y);
        acc.z = fmaf(w, hv.z, acc.z);
        acc.w = fmaf(w, hv.w, acc.w);
    }
    // butterfly-reduce across the 4 lane-groups
#pragma unroll
    for (int off = 16; off < 64; off <<= 1) {
        acc.x += __shfl_xor(acc.x, off);
        acc.y += __shfl_xor(acc.y, off);
        acc.z += __shfl_xor(acc.z, off);
        acc.w += __shfl_xor(acc.w, off);
    }
    if (grp == 0) {
        float4 self = *(const float4*)&hW[n * H + c4];
        float  di   = dinv[n];
        float  di2  = di * di;
        float4 gv = *(const float4*)&g[c4];
        float4 vv = *(const float4*)&v[c4];
        float4 bv = *(const float4*)&b[c4];
        float4 mv = *(const float4*)&m[c4];
        float4 bev= *(const float4*)&be[c4];
        float4 sc, sh, r2;
        sc.x = gv.x * rsqrtf(vv.x + BN_EPS);
        sc.y = gv.y * rsqrtf(vv.y + BN_EPS);
        sc.z = gv.z * rsqrtf(vv.z + BN_EPS);
        sc.w = gv.w * rsqrtf(vv.w + BN_EPS);
        sh.x = bev.x + (bv.x - mv.x) * sc.x;
        sh.y = bev.y + (bv.y - mv.y) * sc.y;
        sh.z = bev.z + (bv.z - mv.z) * sc.z;
        sh.w = bev.w + (bv.w - mv.w) * sc.w;
        r2.x = fmaxf((acc.x + self.x * di2) * sc.x + sh.x, 0.f);
        r2.y = fmaxf((acc.y + self.y * di2) * sc.y + sh.y, 0.f);
        r2.z = fmaxf((acc.z + self.z * di2) * sc.z + sh.z, 0.f);
        r2.w = fmaxf((acc.w + self.w * di2) * sc.w + sh.w, 0.f);
        *(float4*)&hout[n * H + c4] = r2;
    }
}

// ---------------------------------------------------------------- segmented mean pool
// batch is sorted: each wave owns 128 contiguous nodes, flushes on boundary.
#define PCHUNK 128
__global__ void pool_kernel(const float* __restrict__ h, const int* __restrict__ batch,
                            float* __restrict__ pooled, float* __restrict__ counts) {
    int tid  = threadIdx.x;
    int wid  = blockIdx.x * 4 + (tid >> 6);
    int lane = tid & 63;
    int n0   = wid * PCHUNK;
    if (n0 >= N_NODES) return;
    int n1 = min(n0 + PCHUNK, N_NODES);

    int   curb = batch[n0];
    float acc  = 0.0f;
    int   run  = 0;
    for (int n = n0; n < n1; ++n) {
        int bb = batch[n];
        if (bb != curb) {
            atomicAdd(&pooled[curb * H + lane], acc);
            if (lane == 0) atomicAdd(&counts[curb], (float)run);
            acc = 0.0f; run = 0; curb = bb;
        }
        acc += h[n * H + lane];
        ++run;
    }
    atomicAdd(&pooled[curb * H + lane], acc);
    if (lane == 0) atomicAdd(&counts[curb], (float)run);
}

// ---------------------------------------------------------------- final MLP
__global__ void mlp_kernel(const float* __restrict__ pooled, const float* __restrict__ counts,
                           const float* __restrict__ fw1, const float* __restrict__ fb1,
                           const float* __restrict__ fw2, const float* __restrict__ fb2,
                           float* __restrict__ out) {
    __shared__ float prow[H];
    __shared__ float hid[H / 2];
    int b = blockIdx.x;
    int t = threadIdx.x;
    float cnt = fmaxf(counts[b], 1.0f);
    prow[t] = pooled[b * H + t] / cnt;
    __syncthreads();
    if (t < H / 2) {
        float acc = fb1[t];
#pragma unroll
        for (int k = 0; k < H; ++k) acc += prow[k] * fw1[k * (H / 2) + t];
        hid[t] = fmaxf(acc, 0.0f);
    }
    __syncthreads();
    if (t < C_CLS) {
        float acc = fb2[t];
#pragma unroll
        for (int j = 0; j < H / 2; ++j) acc += hid[j] * fw2[j * C_CLS + t];
        out[b * C_CLS + t] = acc;
    }
}

// ================================================================ launch
extern "C" void kernel_launch(void* const* d_in, const int* in_sizes, int n_in,
                              void* d_out, int out_size, void* d_ws, size_t ws_size,
                              hipStream_t stream) {
    const float* x          = (const float*)d_in[0];
    const int*   edge_index = (const int*)d_in[1];
    const int*   batch      = (const int*)d_in[2];

    const float* W1 = (const float*)d_in[3];
    const float* b1 = (const float*)d_in[4];
    const float* g1 = (const float*)d_in[5];
    const float* be1= (const float*)d_in[6];
    const float* m1 = (const float*)d_in[7];
    const float* v1 = (const float*)d_in[8];
    const float* W2 = (const float*)d_in[9];
    const float* b2 = (const float*)d_in[10];
    const float* g2 = (const float*)d_in[11];
    const float* be2= (const float*)d_in[12];
    const float* m2 = (const float*)d_in[13];
    const float* v2 = (const float*)d_in[14];
    const float* W3 = (const float*)d_in[15];
    const float* b3 = (const float*)d_in[16];
    const float* g3 = (const float*)d_in[17];
    const float* be3= (const float*)d_in[18];
    const float* m3 = (const float*)d_in[19];
    const float* v3 = (const float*)d_in[20];
    const float* fw1= (const float*)d_in[21];
    const float* fb1= (const float*)d_in[22];
    const float* fw2= (const float*)d_in[23];
    const float* fb2= (const float*)d_in[24];

    const int* src = edge_index;            // edge_index[0, :]
    const int* dst = edge_index + E_EDGES;  // edge_index[1, :]

    // ---------------- workspace carve-up (floats) ----------------
    float* ws      = (float*)d_ws;
    float* hW      = ws;                          // NH
    float* hbuf    = ws + (size_t)NH;             // NH
    float2* edata  = (float2*)(ws + 2 * (size_t)NH);        // E float2 (8B aligned)
    float* fafter  = ws + 2 * (size_t)NH + 2 * (size_t)E_EDGES;
    int*   deg_i   = (int*)fafter;                // N
    float* dinv    = fafter + N_NODES;            // N
    int*   rowptr  = (int*)(fafter + 2 * N_NODES);// N+1
    int*   cursor  = (int*)(fafter + 3 * N_NODES + 1); // N
    int*   blockSums = (int*)(fafter + 4 * N_NODES + 1); // 512
    int*   blockOff  = blockSums + 512;           // 512
    float* pooled  = fafter + 4 * N_NODES + 1 + 1024;    // B*H
    float* counts  = pooled + B_GR * H;           // B

    float* out = (float*)d_out;

    // ---------------- degree / dinv / CSR build ----------------
    hipMemsetAsync(deg_i, 0, N_NODES * sizeof(int), stream);
    hipMemsetAsync(pooled, 0, (B_GR * H + B_GR) * sizeof(float), stream);

    deg_kernel<<<(E_EDGES + 255) / 256, 256, 0, stream>>>(dst, deg_i);
    dinv_kernel<<<(N_NODES + 255) / 256, 256, 0, stream>>>(deg_i, dinv);

    scan1_kernel<<<NBLK_SCAN, 256, 0, stream>>>(deg_i, rowptr, blockSums);
    scan2_kernel<<<1, 512, 0, stream>>>(blockSums, blockOff);
    scan3_kernel<<<(N_NODES + 256) / 256, 256, 0, stream>>>(rowptr, blockOff, cursor);
    scatter_kernel<<<(E_EDGES + 255) / 256, 256, 0, stream>>>(src, dst, dinv, cursor, edata);

    const int mmGrid   = N_NODES / 16;   // 6250
    const int gGrid    = N_NODES / 4;    // 25000

    // ---- layer 1
    matmul_kernel<F_IN><<<mmGrid, 256, 0, stream>>>(x, W1, hW);
    gather_kernel<<<gGrid, 256, 0, stream>>>(rowptr, edata, hW, dinv, b1, g1, be1, m1, v1, hbuf);
    // ---- layer 2
    matmul_kernel<H><<<mmGrid, 256, 0, stream>>>(hbuf, W2, hW);
    gather_kernel<<<gGrid, 256, 0, stream>>>(rowptr, edata, hW, dinv, b2, g2, be2, m2, v2, hbuf);
    // ---- layer 3
    matmul_kernel<H><<<mmGrid, 256, 0, stream>>>(hbuf, W3, hW);
    gather_kernel<<<gGrid, 256, 0, stream>>>(rowptr, edata, hW, dinv, b3, g3, be3, m3, v3, hbuf);

    // ---- pool + MLP head
    const int poolWaves = (N_NODES + PCHUNK - 1) / PCHUNK;          // 782
    pool_kernel<<<(poolWaves + 3) / 4, 256, 0, stream>>>(hbuf, batch, pooled, counts);
    mlp_kernel<<<B_GR, 64, 0, stream>>>(pooled, counts, fw1, fb1, fw2, fb2, out);
}

// Round 7
// 558.358 us; speedup vs baseline: 3.7565x; 1.0837x over previous
//
#include <hip/hip_runtime.h>
#include <hip/hip_bf16.h>

#define N_NODES 100000
#define E_EDGES 1600000
#define F_IN    10
#define H       64
#define B_GR    128
#define C_CLS   3
#define BN_EPS  1e-5f
#define NH      (N_NODES * H)
#define NBLK_SCAN ((N_NODES + 255) / 256)   // 391

// scatter slicing: 256 chunks x 8 dst-slices
#define SCAT_CHUNKS 256
#define SCAT_PER    (E_EDGES / SCAT_CHUNKS)   // 6250
#define SLICE_N     (N_NODES / 8)             // 12500

// ---------------------------------------------------------------- degree (int)
__global__ void deg_kernel(const int* __restrict__ dst, int* __restrict__ deg) {
    int e = blockIdx.x * blockDim.x + threadIdx.x;
    if (e < E_EDGES) atomicAdd(&deg[dst[e]], 1);
}

__global__ void dinv_kernel(const int* __restrict__ deg, float* __restrict__ dinv) {
    int n = blockIdx.x * blockDim.x + threadIdx.x;
    if (n < N_NODES) dinv[n] = rsqrtf((float)deg[n] + 1.0f);
}

// ---------------------------------------------------------------- scan (CSR rowptr)
__global__ void scan1_kernel(const int* __restrict__ deg, int* __restrict__ rowptr,
                             int* __restrict__ blockSums) {
    __shared__ int lds[256];
    int t = threadIdx.x;
    int i = blockIdx.x * 256 + t;
    int v = (i < N_NODES) ? deg[i] : 0;
    lds[t] = v;
    __syncthreads();
    for (int off = 1; off < 256; off <<= 1) {
        int add = (t >= off) ? lds[t - off] : 0;
        __syncthreads();
        lds[t] += add;
        __syncthreads();
    }
    if (i < N_NODES) rowptr[i] = lds[t] - v;
    if (t == 255) blockSums[blockIdx.x] = lds[255];
}

__global__ void scan2_kernel(const int* __restrict__ blockSums, int* __restrict__ blockOff) {
    __shared__ int lds[512];
    int t = threadIdx.x;
    int v = (t < NBLK_SCAN) ? blockSums[t] : 0;
    lds[t] = v;
    __syncthreads();
    for (int off = 1; off < 512; off <<= 1) {
        int add = (t >= off) ? lds[t - off] : 0;
        __syncthreads();
        lds[t] += add;
        __syncthreads();
    }
    if (t < NBLK_SCAN) blockOff[t] = lds[t] - v;
}

__global__ void scan3_kernel(int* __restrict__ rowptr, const int* __restrict__ blockOff,
                             int* __restrict__ cursor) {
    int i = blockIdx.x * blockDim.x + threadIdx.x;
    if (i < N_NODES) {
        int r = rowptr[i] + blockOff[i >> 8];
        rowptr[i] = r;
        cursor[i] = r;
    } else if (i == N_NODES) {
        rowptr[N_NODES] = E_EDGES;
    }
}

// ---------------------------------------------------------------- CSR scatter (XCD-sliced)
// grid = SCAT_CHUNKS*8. slice = bid&7 owns dst in [slice*SLICE_N, +SLICE_N).
// Each block re-reads its whole edge chunk (8x seq read, cheap) but writes only
// slice-local slots -> under round-robin block->XCD dispatch, each edata line is
// dirtied by a single XCD -> no 8x partial-line writeback amplification.
__global__ __launch_bounds__(256) void scatter_kernel(const int* __restrict__ src,
                                                      const int* __restrict__ dst,
                                                      const float* __restrict__ dinv,
                                                      int* __restrict__ cursor,
                                                      float2* __restrict__ edata) {
    int slice = blockIdx.x & 7;
    int chunk = blockIdx.x >> 3;
    int base  = chunk * SCAT_PER;
    int lo    = slice * SLICE_N;
    int hi    = lo + SLICE_N;
    for (int i = threadIdx.x; i < SCAT_PER; i += 256) {
        int e = base + i;
        int d = dst[e];
        if (d >= lo && d < hi) {
            int s    = src[e];
            int slot = atomicAdd(&cursor[d], 1);
            edata[slot] = make_float2(__int_as_float(s), dinv[s] * dinv[d]);
        }
    }
}

// ---------------------------------------------------------------- layer-1: pad x to N x 16
__global__ void pad_kernel(const float* __restrict__ x, float* __restrict__ xp) {
    int idx = blockIdx.x * blockDim.x + threadIdx.x;
    if (idx >= N_NODES * 16) return;
    int n = idx >> 4, c = idx & 15;
    xp[idx] = (c < F_IN) ? x[n * F_IN + c] : 0.0f;
}

// ---------------------------------------------------------------- layer-1 gather on raw x (16-wide)
// wave per node; 16 groups of 4 lanes, 16 edges/iter, 64B row per edge.
__global__ __launch_bounds__(256) void gather16_kernel(const int* __restrict__ rowptr,
                                                       const float2* __restrict__ edata,
                                                       const float* __restrict__ xp,
                                                       const float* __restrict__ dinv,
                                                       float* __restrict__ agg16) {
    int tid  = threadIdx.x;
    int n    = blockIdx.x * 4 + (tid >> 6);
    if (n >= N_NODES) return;
    int lane = tid & 63;
    int grp  = lane >> 2;          // 0..15
    int c4   = (lane & 3) * 4;     // 0,4,8,12

    int start = rowptr[n], end = rowptr[n + 1];
    float4 acc = make_float4(0.f, 0.f, 0.f, 0.f);
    for (int p = start; p < end; p += 16) {
        int q = p + grp;
        float2 ed = (q < end) ? edata[q] : make_float2(__int_as_float(0), 0.0f);
        int   s = __float_as_int(ed.x);
        float w = ed.y;
        float4 hv = *(const float4*)&xp[s * 16 + c4];
        acc.x = fmaf(w, hv.x, acc.x);
        acc.y = fmaf(w, hv.y, acc.y);
        acc.z = fmaf(w, hv.z, acc.z);
        acc.w = fmaf(w, hv.w, acc.w);
    }
#pragma unroll
    for (int off = 4; off < 64; off <<= 1) {
        acc.x += __shfl_xor(acc.x, off);
        acc.y += __shfl_xor(acc.y, off);
        acc.z += __shfl_xor(acc.z, off);
        acc.w += __shfl_xor(acc.w, off);
    }
    if (grp == 0) {
        float4 self = *(const float4*)&xp[n * 16 + c4];
        float  di   = dinv[n];
        float  di2  = di * di;
        acc.x = fmaf(self.x, di2, acc.x);
        acc.y = fmaf(self.y, di2, acc.y);
        acc.z = fmaf(self.z, di2, acc.z);
        acc.w = fmaf(self.w, di2, acc.w);
        *(float4*)&agg16[n * 16 + c4] = acc;
    }
}

// ---------------------------------------------------------------- layer-1 matmul + bias + BN + ReLU
// agg16 (N x 16, K=10 valid) @ W1 (10 x 64), fused epilogue.
__global__ __launch_bounds__(256) void matmul16_bn_kernel(const float* __restrict__ agg16,
                                                          const float* __restrict__ W,
                                                          const float* __restrict__ b,
                                                          const float* __restrict__ g,
                                                          const float* __restrict__ be,
                                                          const float* __restrict__ m,
                                                          const float* __restrict__ v,
                                                          float* __restrict__ hout) {
    __shared__ float rowLds[16 * 16];
    __shared__ float Wlds[F_IN * 68];
    int tid  = threadIdx.x;
    int base = blockIdx.x * 16;

    if (tid < 64) {
        int r = tid >> 2, c = (tid & 3) * 4;
        *(float4*)&rowLds[r * 16 + c] = *(const float4*)&agg16[(base + r) * 16 + c];
    }
    for (int i = tid; i < F_IN * 64; i += 256) {
        int k = i >> 6, c = i & 63;
        Wlds[k * 68 + c] = W[i];
    }
    __syncthreads();

    int r  = tid >> 4;
    int c4 = (tid & 15) * 4;
    float4 acc = make_float4(0.f, 0.f, 0.f, 0.f);
#pragma unroll
    for (int k = 0; k < F_IN; ++k) {
        float  rv = rowLds[r * 16 + k];
        float4 wv = *(const float4*)&Wlds[k * 68 + c4];
        acc.x = fmaf(rv, wv.x, acc.x);
        acc.y = fmaf(rv, wv.y, acc.y);
        acc.z = fmaf(rv, wv.z, acc.z);
        acc.w = fmaf(rv, wv.w, acc.w);
    }
    float4 gv = *(const float4*)&g[c4];
    float4 vv = *(const float4*)&v[c4];
    float4 bv = *(const float4*)&b[c4];
    float4 mv = *(const float4*)&m[c4];
    float4 bev= *(const float4*)&be[c4];
    float4 sc, sh, r2;
    sc.x = gv.x * rsqrtf(vv.x + BN_EPS);
    sc.y = gv.y * rsqrtf(vv.y + BN_EPS);
    sc.z = gv.z * rsqrtf(vv.z + BN_EPS);
    sc.w = gv.w * rsqrtf(vv.w + BN_EPS);
    sh.x = bev.x + (bv.x - mv.x) * sc.x;
    sh.y = bev.y + (bv.y - mv.y) * sc.y;
    sh.z = bev.z + (bv.z - mv.z) * sc.z;
    sh.w = bev.w + (bv.w - mv.w) * sc.w;
    r2.x = fmaxf(acc.x * sc.x + sh.x, 0.f);
    r2.y = fmaxf(acc.y * sc.y + sh.y, 0.f);
    r2.z = fmaxf(acc.z * sc.z + sh.z, 0.f);
    r2.w = fmaxf(acc.w * sc.w + sh.w, 0.f);
    *(float4*)&hout[(base + r) * H + c4] = r2;
}

// ---------------------------------------------------------------- dense h @ W (H=64), layers 2/3
template <int K>
__global__ __launch_bounds__(256) void matmul_kernel(const float* __restrict__ hin,
                                                     const float* __restrict__ W,
                                                     float* __restrict__ hout) {
    constexpr int KP = (K == 64) ? 65 : (K + 1);
    __shared__ float rowLds[16 * KP];
    __shared__ float Wlds[K * 68];
    int tid  = threadIdx.x;
    int base = blockIdx.x * 16;

    for (int i = tid; i < K * 64; i += 256)
        Wlds[(i >> 6) * 68 + (i & 63)] = W[i];
    for (int i = tid; i < 16 * K; i += 256) {
        int r = i / K, k = i - r * K;
        rowLds[r * KP + k] = hin[(base + r) * K + k];
    }
    __syncthreads();

    int r  = tid >> 4;
    int c4 = (tid & 15) * 4;
    float4 acc = make_float4(0.f, 0.f, 0.f, 0.f);
#pragma unroll
    for (int k = 0; k < K; ++k) {
        float  rv = rowLds[r * KP + k];
        float4 wv = *(const float4*)&Wlds[k * 68 + c4];
        acc.x = fmaf(rv, wv.x, acc.x);
        acc.y = fmaf(rv, wv.y, acc.y);
        acc.z = fmaf(rv, wv.z, acc.z);
        acc.w = fmaf(rv, wv.w, acc.w);
    }
    *(float4*)&hout[(base + r) * H + c4] = acc;
}

// ---------------------------------------------------------------- CSR gather + self + BN + ReLU (H=64)
__global__ __launch_bounds__(256) void gather_kernel(const int* __restrict__ rowptr,
                                                     const float2* __restrict__ edata,
                                                     const float* __restrict__ hW,
                                                     const float* __restrict__ dinv,
                                                     const float* __restrict__ b,
                                                     const float* __restrict__ g,
                                                     const float* __restrict__ be,
                                                     const float* __restrict__ m,
                                                     const float* __restrict__ v,
                                                     float* __restrict__ hout) {
    int tid  = threadIdx.x;
    int n    = blockIdx.x * 4 + (tid >> 6);
    if (n >= N_NODES) return;
    int lane = tid & 63;
    int grp  = lane >> 4;
    int c4   = (lane & 15) * 4;

    int start = rowptr[n], end = rowptr[n + 1];
    float4 acc = make_float4(0.f, 0.f, 0.f, 0.f);
    for (int p = start; p < end; p += 4) {
        int q = p + grp;
        float2 ed = (q < end) ? edata[q] : make_float2(__int_as_float(0), 0.0f);
        int   s = __float_as_int(ed.x);
        float w = ed.y;
        float4 hv = *(const float4*)&hW[s * H + c4];
        acc.x = fmaf(w, hv.x, acc.x);
        acc.y = fmaf(w, hv.y, acc.y);
        acc.z = fmaf(w, hv.z, acc.z);
        acc.w = fmaf(w, hv.w, acc.w);
    }
#pragma unroll
    for (int off = 16; off < 64; off <<= 1) {
        acc.x += __shfl_xor(acc.x, off);
        acc.y += __shfl_xor(acc.y, off);
        acc.z += __shfl_xor(acc.z, off);
        acc.w += __shfl_xor(acc.w, off);
    }
    if (grp == 0) {
        float4 self = *(const float4*)&hW[n * H + c4];
        float  di   = dinv[n];
        float  di2  = di * di;
        float4 gv = *(const float4*)&g[c4];
        float4 vv = *(const float4*)&v[c4];
        float4 bv = *(const float4*)&b[c4];
        float4 mv = *(const float4*)&m[c4];
        float4 bev= *(const float4*)&be[c4];
        float4 sc, sh, r2;
        sc.x = gv.x * rsqrtf(vv.x + BN_EPS);
        sc.y = gv.y * rsqrtf(vv.y + BN_EPS);
        sc.z = gv.z * rsqrtf(vv.z + BN_EPS);
        sc.w = gv.w * rsqrtf(vv.w + BN_EPS);
        sh.x = bev.x + (bv.x - mv.x) * sc.x;
        sh.y = bev.y + (bv.y - mv.y) * sc.y;
        sh.z = bev.z + (bv.z - mv.z) * sc.z;
        sh.w = bev.w + (bv.w - mv.w) * sc.w;
        r2.x = fmaxf((acc.x + self.x * di2) * sc.x + sh.x, 0.f);
        r2.y = fmaxf((acc.y + self.y * di2) * sc.y + sh.y, 0.f);
        r2.z = fmaxf((acc.z + self.z * di2) * sc.z + sh.z, 0.f);
        r2.w = fmaxf((acc.w + self.w * di2) * sc.w + sh.w, 0.f);
        *(float4*)&hout[n * H + c4] = r2;
    }
}

// ---------------------------------------------------------------- segmented mean pool
#define PCHUNK 128
__global__ void pool_kernel(const float* __restrict__ h, const int* __restrict__ batch,
                            float* __restrict__ pooled, float* __restrict__ counts) {
    int tid  = threadIdx.x;
    int wid  = blockIdx.x * 4 + (tid >> 6);
    int lane = tid & 63;
    int n0   = wid * PCHUNK;
    if (n0 >= N_NODES) return;
    int n1 = min(n0 + PCHUNK, N_NODES);

    int   curb = batch[n0];
    float acc  = 0.0f;
    int   run  = 0;
    for (int n = n0; n < n1; ++n) {
        int bb = batch[n];
        if (bb != curb) {
            atomicAdd(&pooled[curb * H + lane], acc);
            if (lane == 0) atomicAdd(&counts[curb], (float)run);
            acc = 0.0f; run = 0; curb = bb;
        }
        acc += h[n * H + lane];
        ++run;
    }
    atomicAdd(&pooled[curb * H + lane], acc);
    if (lane == 0) atomicAdd(&counts[curb], (float)run);
}

// ---------------------------------------------------------------- final MLP
__global__ void mlp_kernel(const float* __restrict__ pooled, const float* __restrict__ counts,
                           const float* __restrict__ fw1, const float* __restrict__ fb1,
                           const float* __restrict__ fw2, const float* __restrict__ fb2,
                           float* __restrict__ out) {
    __shared__ float prow[H];
    __shared__ float hid[H / 2];
    int b = blockIdx.x;
    int t = threadIdx.x;
    float cnt = fmaxf(counts[b], 1.0f);
    prow[t] = pooled[b * H + t] / cnt;
    __syncthreads();
    if (t < H / 2) {
        float acc = fb1[t];
#pragma unroll
        for (int k = 0; k < H; ++k) acc += prow[k] * fw1[k * (H / 2) + t];
        hid[t] = fmaxf(acc, 0.0f);
    }
    __syncthreads();
    if (t < C_CLS) {
        float acc = fb2[t];
#pragma unroll
        for (int j = 0; j < H / 2; ++j) acc += hid[j] * fw2[j * C_CLS + t];
        out[b * C_CLS + t] = acc;
    }
}

// ================================================================ launch
extern "C" void kernel_launch(void* const* d_in, const int* in_sizes, int n_in,
                              void* d_out, int out_size, void* d_ws, size_t ws_size,
                              hipStream_t stream) {
    const float* x          = (const float*)d_in[0];
    const int*   edge_index = (const int*)d_in[1];
    const int*   batch      = (const int*)d_in[2];

    const float* W1 = (const float*)d_in[3];
    const float* b1 = (const float*)d_in[4];
    const float* g1 = (const float*)d_in[5];
    const float* be1= (const float*)d_in[6];
    const float* m1 = (const float*)d_in[7];
    const float* v1 = (const float*)d_in[8];
    const float* W2 = (const float*)d_in[9];
    const float* b2 = (const float*)d_in[10];
    const float* g2 = (const float*)d_in[11];
    const float* be2= (const float*)d_in[12];
    const float* m2 = (const float*)d_in[13];
    const float* v2 = (const float*)d_in[14];
    const float* W3 = (const float*)d_in[15];
    const float* b3 = (const float*)d_in[16];
    const float* g3 = (const float*)d_in[17];
    const float* be3= (const float*)d_in[18];
    const float* m3 = (const float*)d_in[19];
    const float* v3 = (const float*)d_in[20];
    const float* fw1= (const float*)d_in[21];
    const float* fb1= (const float*)d_in[22];
    const float* fw2= (const float*)d_in[23];
    const float* fb2= (const float*)d_in[24];

    const int* src = edge_index;            // edge_index[0, :]
    const int* dst = edge_index + E_EDGES;  // edge_index[1, :]

    // ---------------- workspace carve-up (floats) ----------------
    float* ws      = (float*)d_ws;
    float* hW      = ws;                          // NH (layer-2/3); layer-1 reuses: xp, agg16
    float* hbuf    = ws + (size_t)NH;             // NH
    float2* edata  = (float2*)(ws + 2 * (size_t)NH);        // E float2
    float* fafter  = ws + 2 * (size_t)NH + 2 * (size_t)E_EDGES;
    int*   deg_i   = (int*)fafter;                // N
    float* dinv    = fafter + N_NODES;            // N
    int*   rowptr  = (int*)(fafter + 2 * N_NODES);// N+1
    int*   cursor  = (int*)(fafter + 3 * N_NODES + 1); // N
    int*   blockSums = (int*)(fafter + 4 * N_NODES + 1); // 512
    int*   blockOff  = blockSums + 512;           // 512
    float* pooled  = fafter + 4 * N_NODES + 1 + 1024;    // B*H
    float* counts  = pooled + B_GR * H;           // B

    float* xp    = hW;                  // N*16  (layer-1 only, before hW is written)
    float* agg16 = hW + (size_t)N_NODES * 16;   // N*16

    float* out = (float*)d_out;

    // ---------------- degree / dinv / CSR build ----------------
    hipMemsetAsync(deg_i, 0, N_NODES * sizeof(int), stream);
    hipMemsetAsync(pooled, 0, (B_GR * H + B_GR) * sizeof(float), stream);

    deg_kernel<<<(E_EDGES + 255) / 256, 256, 0, stream>>>(dst, deg_i);
    dinv_kernel<<<(N_NODES + 255) / 256, 256, 0, stream>>>(deg_i, dinv);

    scan1_kernel<<<NBLK_SCAN, 256, 0, stream>>>(deg_i, rowptr, blockSums);
    scan2_kernel<<<1, 512, 0, stream>>>(blockSums, blockOff);
    scan3_kernel<<<(N_NODES + 256) / 256, 256, 0, stream>>>(rowptr, blockOff, cursor);
    scatter_kernel<<<SCAT_CHUNKS * 8, 256, 0, stream>>>(src, dst, dinv, cursor, edata);

    const int mmGrid = N_NODES / 16;   // 6250
    const int gGrid  = N_NODES / 4;    // 25000

    // ---- layer 1: aggregate raw x (16-wide) then matmul+BN+ReLU
    pad_kernel<<<(N_NODES * 16 + 255) / 256, 256, 0, stream>>>(x, xp);
    gather16_kernel<<<gGrid, 256, 0, stream>>>(rowptr, edata, xp, dinv, agg16);
    matmul16_bn_kernel<<<mmGrid, 256, 0, stream>>>(agg16, W1, b1, g1, be1, m1, v1, hbuf);

    // ---- layer 2
    matmul_kernel<H><<<mmGrid, 256, 0, stream>>>(hbuf, W2, hW);
    gather_kernel<<<gGrid, 256, 0, stream>>>(rowptr, edata, hW, dinv, b2, g2, be2, m2, v2, hbuf);

    // ---- layer 3
    matmul_kernel<H><<<mmGrid, 256, 0, stream>>>(hbuf, W3, hW);
    gather_kernel<<<gGrid, 256, 0, stream>>>(rowptr, edata, hW, dinv, b3, g3, be3, m3, v3, hbuf);

    // ---- pool + MLP head
    const int poolWaves = (N_NODES + PCHUNK - 1) / PCHUNK;
    pool_kernel<<<(poolWaves + 3) / 4, 256, 0, stream>>>(hbuf, batch, pooled, counts);
    mlp_kernel<<<B_GR, 64, 0, stream>>>(pooled, counts, fw1, fb1, fw2, fb2, out);
}

// Round 10
// 524.785 us; speedup vs baseline: 3.9968x; 1.0640x over previous
//
#include <hip/hip_runtime.h>
#include <hip/hip_bf16.h>

#define N_NODES 100000
#define E_EDGES 1600000
#define F_IN    10
#define H       64
#define B_GR    128
#define C_CLS   3
#define BN_EPS  1e-5f
#define NH      (N_NODES * H)
#define NBLK_SCAN ((N_NODES + 255) / 256)   // 391

// two-level CSR build
#define TILE1   4096
#define NB1     391           // ceil(N/256): coarse buckets of 256 dst nodes
#define L2CAP   6144          // bucket edge cap (mean 4096, sigma 64 -> +32 sigma)

// ---------------------------------------------------------------- degree (int)
__global__ void deg_kernel(const int* __restrict__ dst, int* __restrict__ deg) {
    int e = blockIdx.x * blockDim.x + threadIdx.x;
    if (e < E_EDGES) atomicAdd(&deg[dst[e]], 1);
}

__global__ void dinv_kernel(const int* __restrict__ deg, float* __restrict__ dinv) {
    int n = blockIdx.x * blockDim.x + threadIdx.x;
    if (n < N_NODES) dinv[n] = rsqrtf((float)deg[n] + 1.0f);
}

// ---------------------------------------------------------------- scan (CSR rowptr)
__global__ void scan1_kernel(const int* __restrict__ deg, int* __restrict__ rowptr,
                             int* __restrict__ blockSums) {
    __shared__ int lds[256];
    int t = threadIdx.x;
    int i = blockIdx.x * 256 + t;
    int v = (i < N_NODES) ? deg[i] : 0;
    lds[t] = v;
    __syncthreads();
    for (int off = 1; off < 256; off <<= 1) {
        int add = (t >= off) ? lds[t - off] : 0;
        __syncthreads();
        lds[t] += add;
        __syncthreads();
    }
    if (i < N_NODES) rowptr[i] = lds[t] - v;
    if (t == 255) blockSums[blockIdx.x] = lds[255];
}

__global__ void scan2_kernel(const int* __restrict__ blockSums, int* __restrict__ blockOff) {
    __shared__ int lds[512];
    int t = threadIdx.x;
    int v = (t < NBLK_SCAN) ? blockSums[t] : 0;
    lds[t] = v;
    __syncthreads();
    for (int off = 1; off < 512; off <<= 1) {
        int add = (t >= off) ? lds[t - off] : 0;
        __syncthreads();
        lds[t] += add;
        __syncthreads();
    }
    if (t < NBLK_SCAN) blockOff[t] = lds[t] - v;
}

// finalize rowptr, emit rowptr[N]=E, init coarse-bucket cursors from rowptr.
__global__ void scan3_kernel(int* __restrict__ rowptr, const int* __restrict__ blockOff,
                             int* __restrict__ bcur) {
    int i = blockIdx.x * blockDim.x + threadIdx.x;
    if (i < N_NODES) {
        int r = rowptr[i] + blockOff[i >> 8];
        rowptr[i] = r;
        if ((i & 255) == 0) bcur[i >> 8] = r;
    } else if (i == N_NODES) {
        rowptr[N_NODES] = E_EDGES;
    }
}

// ---------------------------------------------------------------- L1: tile -> coarse buckets
// Block sorts its 4096-edge tile by bucket (dst>>8) in LDS, then appends each
// bucket's chunk to that bucket's global region (coalesced runs, ~4B/edge).
__global__ __launch_bounds__(256) void l1sort_kernel(const int* __restrict__ src,
                                                     const int* __restrict__ dst,
                                                     int* __restrict__ bcur,
                                                     int* __restrict__ inter) {
    __shared__ int hist[NB1];
    __shared__ int sbase[NB1];
    __shared__ int gbase[NB1];
    __shared__ int scanA[512];
    __shared__ int scanB[512];
    __shared__ int ebuf[TILE1];
    __shared__ unsigned short bkt[TILE1];

    int tid   = threadIdx.x;
    int tbase = blockIdx.x * TILE1;
    int tcnt  = min(TILE1, E_EDGES - tbase);

    for (int i = tid; i < NB1; i += 256) hist[i] = 0;
    __syncthreads();

    int   pk[16];
    int   rk[16];
    short bb[16];
#pragma unroll
    for (int j = 0; j < 16; ++j) {
        int i = j * 256 + tid;
        if (i < tcnt) {
            int e = tbase + i;
            int s = src[e], d = dst[e];
            int b  = d >> 8;
            int dl = d & 255;
            pk[j] = s | (dl << 17);          // s:17 bits, d_local:8 bits
            bb[j] = (short)b;
            rk[j] = atomicAdd(&hist[b], 1);
        } else {
            pk[j] = -1; rk[j] = 0; bb[j] = 0;
        }
    }
    __syncthreads();

    // inclusive scan of hist (ping-pong Hillis-Steele over 512 slots)
    for (int i = tid; i < 512; i += 256) scanA[i] = (i < NB1) ? hist[i] : 0;
    __syncthreads();
    int* A = scanA; int* B = scanB;
    for (int off = 1; off < 512; off <<= 1) {
        for (int i = tid; i < 512; i += 256)
            B[i] = A[i] + ((i >= off) ? A[i - off] : 0);
        __syncthreads();
        int* t = A; A = B; B = t;
    }
    for (int i = tid; i < NB1; i += 256) {
        int c = hist[i];
        sbase[i] = A[i] - c;                               // exclusive
        gbase[i] = (c > 0) ? atomicAdd(&bcur[i], c) : 0;   // grab global range
    }
    __syncthreads();

    // scatter into LDS (bucket-sorted order within tile)
#pragma unroll
    for (int j = 0; j < 16; ++j) {
        if (pk[j] >= 0) {
            int b   = bb[j];
            int pos = sbase[b] + rk[j];
            ebuf[pos] = pk[j];
            bkt[pos]  = (unsigned short)b;
        }
    }
    __syncthreads();

    // flush: per-bucket contiguous runs -> coalesced global appends
    for (int i = tid; i < tcnt; i += 256) {
        int b = bkt[i];
        inter[gbase[b] + (i - sbase[b])] = ebuf[i];
    }
}

// ---------------------------------------------------------------- L2: bucket -> node-sorted edata
// One block per coarse bucket: node-level counting sort entirely in LDS,
// then a fully coalesced sequential flush of (src, coef) float2 edata.
__global__ __launch_bounds__(256) void l2sort_kernel(const int* __restrict__ rowptr,
                                                     const int* __restrict__ inter,
                                                     const float* __restrict__ dinv,
                                                     float2* __restrict__ edata) {
    __shared__ int    nhist[256];
    __shared__ int    nscan[256];
    __shared__ float2 ebuf[L2CAP];

    int tid      = threadIdx.x;
    int b        = blockIdx.x;
    int nodeBase = b << 8;
    int lo       = rowptr[nodeBase];
    int hi       = rowptr[min(nodeBase + 256, N_NODES)];
    int cnt      = hi - lo;
    if (cnt > L2CAP) cnt = L2CAP;   // statistically impossible; guard anyway

    nhist[tid] = 0;
    __syncthreads();

    int vv[24];
    int dr[24];
#pragma unroll
    for (int j = 0; j < 24; ++j) {
        int i = j * 256 + tid;
        if (i < cnt) {
            int v  = inter[lo + i];
            int dl = (v >> 17) & 255;
            int r  = atomicAdd(&nhist[dl], 1);
            vv[j] = v;
            dr[j] = (dl << 16) | r;
        } else {
            vv[j] = -1; dr[j] = 0;
        }
    }
    __syncthreads();

    // exclusive scan of per-node counts
    int vval = nhist[tid];
    nscan[tid] = vval;
    __syncthreads();
    for (int off = 1; off < 256; off <<= 1) {
        int add = (tid >= off) ? nscan[tid - off] : 0;
        __syncthreads();
        nscan[tid] += add;
        __syncthreads();
    }
    nhist[tid] = nscan[tid] - vval;   // exclusive base per node
    __syncthreads();

#pragma unroll
    for (int j = 0; j < 24; ++j) {
        if (vv[j] >= 0) {
            int dl  = dr[j] >> 16;
            int r   = dr[j] & 0xFFFF;
            int pos = nhist[dl] + r;
            int s   = vv[j] & 0x1FFFF;
            int d   = nodeBase + dl;
            ebuf[pos] = make_float2(__int_as_float(s), dinv[s] * dinv[d]);
        }
    }
    __syncthreads();

    for (int i = tid; i < cnt; i += 256)
        edata[lo + i] = ebuf[i];
}

// ---------------------------------------------------------------- layer-1: pad x to N x 16
__global__ void pad_kernel(const float* __restrict__ x, float* __restrict__ xp) {
    int idx = blockIdx.x * blockDim.x + threadIdx.x;
    if (idx >= N_NODES * 16) return;
    int n = idx >> 4, c = idx & 15;
    xp[idx] = (c < F_IN) ? x[n * F_IN + c] : 0.0f;
}

// ---------------------------------------------------------------- layer-1 gather on raw x (16-wide)
__global__ __launch_bounds__(256) void gather16_kernel(const int* __restrict__ rowptr,
                                                       const float2* __restrict__ edata,
                                                       const float* __restrict__ xp,
                                                       const float* __restrict__ dinv,
                                                       float* __restrict__ agg16) {
    int tid  = threadIdx.x;
    int n    = blockIdx.x * 4 + (tid >> 6);
    if (n >= N_NODES) return;
    int lane = tid & 63;
    int grp  = lane >> 2;          // 0..15
    int c4   = (lane & 3) * 4;     // 0,4,8,12

    int start = rowptr[n], end = rowptr[n + 1];
    float4 acc = make_float4(0.f, 0.f, 0.f, 0.f);
    for (int p = start; p < end; p += 16) {
        int q = p + grp;
        float2 ed = (q < end) ? edata[q] : make_float2(__int_as_float(0), 0.0f);
        int   s = __float_as_int(ed.x);
        float w = ed.y;
        float4 hv = *(const float4*)&xp[s * 16 + c4];
        acc.x = fmaf(w, hv.x, acc.x);
        acc.y = fmaf(w, hv.y, acc.y);
        acc.z = fmaf(w, hv.z, acc.z);
        acc.w = fmaf(w, hv.w, acc.w);
    }
#pragma unroll
    for (int off = 4; off < 64; off <<= 1) {
        acc.x += __shfl_xor(acc.x, off);
        acc.y += __shfl_xor(acc.y, off);
        acc.z += __shfl_xor(acc.z, off);
        acc.w += __shfl_xor(acc.w, off);
    }
    if (grp == 0) {
        float4 self = *(const float4*)&xp[n * 16 + c4];
        float  di   = dinv[n];
        float  di2  = di * di;
        acc.x = fmaf(self.x, di2, acc.x);
        acc.y = fmaf(self.y, di2, acc.y);
        acc.z = fmaf(self.z, di2, acc.z);
        acc.w = fmaf(self.w, di2, acc.w);
        *(float4*)&agg16[n * 16 + c4] = acc;
    }
}

// ---------------------------------------------------------------- layer-1 matmul + bias + BN + ReLU
__global__ __launch_bounds__(256) void matmul16_bn_kernel(const float* __restrict__ agg16,
                                                          const float* __restrict__ W,
                                                          const float* __restrict__ b,
                                                          const float* __restrict__ g,
                                                          const float* __restrict__ be,
                                                          const float* __restrict__ m,
                                                          const float* __restrict__ v,
                                                          float* __restrict__ hout) {
    __shared__ float rowLds[16 * 16];
    __shared__ float Wlds[F_IN * 68];
    int tid  = threadIdx.x;
    int base = blockIdx.x * 16;

    if (tid < 64) {
        int r = tid >> 2, c = (tid & 3) * 4;
        *(float4*)&rowLds[r * 16 + c] = *(const float4*)&agg16[(base + r) * 16 + c];
    }
    for (int i = tid; i < F_IN * 64; i += 256) {
        int k = i >> 6, c = i & 63;
        Wlds[k * 68 + c] = W[i];
    }
    __syncthreads();

    int r  = tid >> 4;
    int c4 = (tid & 15) * 4;
    float4 acc = make_float4(0.f, 0.f, 0.f, 0.f);
#pragma unroll
    for (int k = 0; k < F_IN; ++k) {
        float  rv = rowLds[r * 16 + k];
        float4 wv = *(const float4*)&Wlds[k * 68 + c4];
        acc.x = fmaf(rv, wv.x, acc.x);
        acc.y = fmaf(rv, wv.y, acc.y);
        acc.z = fmaf(rv, wv.z, acc.z);
        acc.w = fmaf(rv, wv.w, acc.w);
    }
    float4 gv = *(const float4*)&g[c4];
    float4 vv = *(const float4*)&v[c4];
    float4 bv = *(const float4*)&b[c4];
    float4 mv = *(const float4*)&m[c4];
    float4 bev= *(const float4*)&be[c4];
    float4 sc, sh, r2;
    sc.x = gv.x * rsqrtf(vv.x + BN_EPS);
    sc.y = gv.y * rsqrtf(vv.y + BN_EPS);
    sc.z = gv.z * rsqrtf(vv.z + BN_EPS);
    sc.w = gv.w * rsqrtf(vv.w + BN_EPS);
    sh.x = bev.x + (bv.x - mv.x) * sc.x;
    sh.y = bev.y + (bv.y - mv.y) * sc.y;
    sh.z = bev.z + (bv.z - mv.z) * sc.z;
    sh.w = bev.w + (bv.w - mv.w) * sc.w;
    r2.x = fmaxf(acc.x * sc.x + sh.x, 0.f);
    r2.y = fmaxf(acc.y * sc.y + sh.y, 0.f);
    r2.z = fmaxf(acc.z * sc.z + sh.z, 0.f);
    r2.w = fmaxf(acc.w * sc.w + sh.w, 0.f);
    *(float4*)&hout[(base + r) * H + c4] = r2;
}

// ---------------------------------------------------------------- dense h @ W (H=64), layers 2/3
template <int K>
__global__ __launch_bounds__(256) void matmul_kernel(const float* __restrict__ hin,
                                                     const float* __restrict__ W,
                                                     float* __restrict__ hout) {
    constexpr int KP = (K == 64) ? 65 : (K + 1);
    __shared__ float rowLds[16 * KP];
    __shared__ float Wlds[K * 68];
    int tid  = threadIdx.x;
    int base = blockIdx.x * 16;

    for (int i = tid; i < K * 64; i += 256)
        Wlds[(i >> 6) * 68 + (i & 63)] = W[i];
    for (int i = tid; i < 16 * K; i += 256) {
        int r = i / K, k = i - r * K;
        rowLds[r * KP + k] = hin[(base + r) * K + k];
    }
    __syncthreads();

    int r  = tid >> 4;
    int c4 = (tid & 15) * 4;
    float4 acc = make_float4(0.f, 0.f, 0.f, 0.f);
#pragma unroll
    for (int k = 0; k < K; ++k) {
        float  rv = rowLds[r * KP + k];
        float4 wv = *(const float4*)&Wlds[k * 68 + c4];
        acc.x = fmaf(rv, wv.x, acc.x);
        acc.y = fmaf(rv, wv.y, acc.y);
        acc.z = fmaf(rv, wv.z, acc.z);
        acc.w = fmaf(rv, wv.w, acc.w);
    }
    *(float4*)&hout[(base + r) * H + c4] = acc;
}

// ---------------------------------------------------------------- CSR gather + self + BN + ReLU (H=64)
__global__ __launch_bounds__(256) void gather_kernel(const int* __restrict__ rowptr,
                                                     const float2* __restrict__ edata,
                                                     const float* __restrict__ hW,
                                                     const float* __restrict__ dinv,
                                                     const float* __restrict__ b,
                                                     const float* __restrict__ g,
                                                     const float* __restrict__ be,
                                                     const float* __restrict__ m,
                                                     const float* __restrict__ v,
                                                     float* __restrict__ hout) {
    int tid  = threadIdx.x;
    int n    = blockIdx.x * 4 + (tid >> 6);
    if (n >= N_NODES) return;
    int lane = tid & 63;
    int grp  = lane >> 4;
    int c4   = (lane & 15) * 4;

    int start = rowptr[n], end = rowptr[n + 1];
    float4 acc = make_float4(0.f, 0.f, 0.f, 0.f);
    for (int p = start; p < end; p += 4) {
        int q = p + grp;
        float2 ed = (q < end) ? edata[q] : make_float2(__int_as_float(0), 0.0f);
        int   s = __float_as_int(ed.x);
        float w = ed.y;
        float4 hv = *(const float4*)&hW[s * H + c4];
        acc.x = fmaf(w, hv.x, acc.x);
        acc.y = fmaf(w, hv.y, acc.y);
        acc.z = fmaf(w, hv.z, acc.z);
        acc.w = fmaf(w, hv.w, acc.w);
    }
#pragma unroll
    for (int off = 16; off < 64; off <<= 1) {
        acc.x += __shfl_xor(acc.x, off);
        acc.y += __shfl_xor(acc.y, off);
        acc.z += __shfl_xor(acc.z, off);
        acc.w += __shfl_xor(acc.w, off);
    }
    if (grp == 0) {
        float4 self = *(const float4*)&hW[n * H + c4];
        float  di   = dinv[n];
        float  di2  = di * di;
        float4 gv = *(const float4*)&g[c4];
        float4 vv = *(const float4*)&v[c4];
        float4 bv = *(const float4*)&b[c4];
        float4 mv = *(const float4*)&m[c4];
        float4 bev= *(const float4*)&be[c4];
        float4 sc, sh, r2;
        sc.x = gv.x * rsqrtf(vv.x + BN_EPS);
        sc.y = gv.y * rsqrtf(vv.y + BN_EPS);
        sc.z = gv.z * rsqrtf(vv.z + BN_EPS);
        sc.w = gv.w * rsqrtf(vv.w + BN_EPS);
        sh.x = bev.x + (bv.x - mv.x) * sc.x;
        sh.y = bev.y + (bv.y - mv.y) * sc.y;
        sh.z = bev.z + (bv.z - mv.z) * sc.z;
        sh.w = bev.w + (bv.w - mv.w) * sc.w;
        r2.x = fmaxf((acc.x + self.x * di2) * sc.x + sh.x, 0.f);
        r2.y = fmaxf((acc.y + self.y * di2) * sc.y + sh.y, 0.f);
        r2.z = fmaxf((acc.z + self.z * di2) * sc.z + sh.z, 0.f);
        r2.w = fmaxf((acc.w + self.w * di2) * sc.w + sh.w, 0.f);
        *(float4*)&hout[n * H + c4] = r2;
    }
}

// ---------------------------------------------------------------- segmented mean pool
#define PCHUNK 128
__global__ void pool_kernel(const float* __restrict__ h, const int* __restrict__ batch,
                            float* __restrict__ pooled, float* __restrict__ counts) {
    int tid  = threadIdx.x;
    int wid  = blockIdx.x * 4 + (tid >> 6);
    int lane = tid & 63;
    int n0   = wid * PCHUNK;
    if (n0 >= N_NODES) return;
    int n1 = min(n0 + PCHUNK, N_NODES);

    int   curb = batch[n0];
    float acc  = 0.0f;
    int   run  = 0;
    for (int n = n0; n < n1; ++n) {
        int bb = batch[n];
        if (bb != curb) {
            atomicAdd(&pooled[curb * H + lane], acc);
            if (lane == 0) atomicAdd(&counts[curb], (float)run);
            acc = 0.0f; run = 0; curb = bb;
        }
        acc += h[n * H + lane];
        ++run;
    }
    atomicAdd(&pooled[curb * H + lane], acc);
    if (lane == 0) atomicAdd(&counts[curb], (float)run);
}

// ---------------------------------------------------------------- final MLP
__global__ void mlp_kernel(const float* __restrict__ pooled, const float* __restrict__ counts,
                           const float* __restrict__ fw1, const float* __restrict__ fb1,
                           const float* __restrict__ fw2, const float* __restrict__ fb2,
                           float* __restrict__ out) {
    __shared__ float prow[H];
    __shared__ float hid[H / 2];
    int b = blockIdx.x;
    int t = threadIdx.x;
    float cnt = fmaxf(counts[b], 1.0f);
    prow[t] = pooled[b * H + t] / cnt;
    __syncthreads();
    if (t < H / 2) {
        float acc = fb1[t];
#pragma unroll
        for (int k = 0; k < H; ++k) acc += prow[k] * fw1[k * (H / 2) + t];
        hid[t] = fmaxf(acc, 0.0f);
    }
    __syncthreads();
    if (t < C_CLS) {
        float acc = fb2[t];
#pragma unroll
        for (int j = 0; j < H / 2; ++j) acc += hid[j] * fw2[j * C_CLS + t];
        out[b * C_CLS + t] = acc;
    }
}

// ================================================================ launch
extern "C" void kernel_launch(void* const* d_in, const int* in_sizes, int n_in,
                              void* d_out, int out_size, void* d_ws, size_t ws_size,
                              hipStream_t stream) {
    const float* x          = (const float*)d_in[0];
    const int*   edge_index = (const int*)d_in[1];
    const int*   batch      = (const int*)d_in[2];

    const float* W1 = (const float*)d_in[3];
    const float* b1 = (const float*)d_in[4];
    const float* g1 = (const float*)d_in[5];
    const float* be1= (const float*)d_in[6];
    const float* m1 = (const float*)d_in[7];
    const float* v1 = (const float*)d_in[8];
    const float* W2 = (const float*)d_in[9];
    const float* b2 = (const float*)d_in[10];
    const float* g2 = (const float*)d_in[11];
    const float* be2= (const float*)d_in[12];
    const float* m2 = (const float*)d_in[13];
    const float* v2 = (const float*)d_in[14];
    const float* W3 = (const float*)d_in[15];
    const float* b3 = (const float*)d_in[16];
    const float* g3 = (const float*)d_in[17];
    const float* be3= (const float*)d_in[18];
    const float* m3 = (const float*)d_in[19];
    const float* v3 = (const float*)d_in[20];
    const float* fw1= (const float*)d_in[21];
    const float* fb1= (const float*)d_in[22];
    const float* fw2= (const float*)d_in[23];
    const float* fb2= (const float*)d_in[24];

    const int* src = edge_index;            // edge_index[0, :]
    const int* dst = edge_index + E_EDGES;  // edge_index[1, :]

    // ---------------- workspace carve-up (floats) ----------------
    float* ws      = (float*)d_ws;
    float* hW      = ws;                          // NH; layer-1 phase reuses as xp/agg16/inter
    float* hbuf    = ws + (size_t)NH;             // NH
    float2* edata  = (float2*)(ws + 2 * (size_t)NH);        // E float2
    float* fafter  = ws + 2 * (size_t)NH + 2 * (size_t)E_EDGES;
    int*   deg_i   = (int*)fafter;                // N
    float* dinv    = fafter + N_NODES;            // N
    int*   rowptr  = (int*)(fafter + 2 * N_NODES);// N+1
    int*   blockSums = (int*)(fafter + 3 * N_NODES + 1); // 512
    int*   blockOff  = blockSums + 512;           // 512
    int*   bcur      = blockOff + 512;            // 512 (NB1=391 used)
    float* pooled  = fafter + 3 * N_NODES + 1 + 1536;    // B*H
    float* counts  = pooled + B_GR * H;           // B

    float* xp    = hW;                                  // N*16 (layer-1 phase)
    float* agg16 = hW + (size_t)N_NODES * 16;           // N*16
    int*   inter = (int*)(hW + 2 * (size_t)N_NODES * 16); // E ints (dead before hW written)

    float* out = (float*)d_out;

    // ---------------- degree / dinv / CSR build ----------------
    hipMemsetAsync(deg_i, 0, N_NODES * sizeof(int), stream);
    hipMemsetAsync(pooled, 0, (B_GR * H + B_GR) * sizeof(float), stream);

    deg_kernel<<<(E_EDGES + 255) / 256, 256, 0, stream>>>(dst, deg_i);
    dinv_kernel<<<(N_NODES + 255) / 256, 256, 0, stream>>>(deg_i, dinv);

    scan1_kernel<<<NBLK_SCAN, 256, 0, stream>>>(deg_i, rowptr, blockSums);
    scan2_kernel<<<1, 512, 0, stream>>>(blockSums, blockOff);
    scan3_kernel<<<(N_NODES + 256) / 256, 256, 0, stream>>>(rowptr, blockOff, bcur);

    l1sort_kernel<<<(E_EDGES + TILE1 - 1) / TILE1, 256, 0, stream>>>(src, dst, bcur, inter);
    l2sort_kernel<<<NB1, 256, 0, stream>>>(rowptr, inter, dinv, edata);

    const int mmGrid = N_NODES / 16;   // 6250
    const int gGrid  = N_NODES / 4;    // 25000

    // ---- layer 1: aggregate raw x (16-wide) then matmul+BN+ReLU
    pad_kernel<<<(N_NODES * 16 + 255) / 256, 256, 0, stream>>>(x, xp);
    gather16_kernel<<<gGrid, 256, 0, stream>>>(rowptr, edata, xp, dinv, agg16);
    matmul16_bn_kernel<<<mmGrid, 256, 0, stream>>>(agg16, W1, b1, g1, be1, m1, v1, hbuf);

    // ---- layer 2
    matmul_kernel<H><<<mmGrid, 256, 0, stream>>>(hbuf, W2, hW);
    gather_kernel<<<gGrid, 256, 0, stream>>>(rowptr, edata, hW, dinv, b2, g2, be2, m2, v2, hbuf);

    // ---- layer 3
    matmul_kernel<H><<<mmGrid, 256, 0, stream>>>(hbuf, W3, hW);
    gather_kernel<<<gGrid, 256, 0, stream>>>(rowptr, edata, hW, dinv, b3, g3, be3, m3, v3, hbuf);

    // ---- pool + MLP head
    const int poolWaves = (N_NODES + PCHUNK - 1) / PCHUNK;
    pool_kernel<<<(poolWaves + 3) / 4, 256, 0, stream>>>(hbuf, batch, pooled, counts);
    mlp_kernel<<<B_GR, 64, 0, stream>>>(pooled, counts, fw1, fb1, fw2, fb2, out);
}

// Round 11
// 499.015 us; speedup vs baseline: 4.2033x; 1.0516x over previous
//
#include <hip/hip_runtime.h>
#include <hip/hip_bf16.h>
#include <hip/hip_fp16.h>

#define N_NODES 100000
#define E_EDGES 1600000
#define F_IN    10
#define H       64
#define B_GR    128
#define C_CLS   3
#define BN_EPS  1e-5f
#define NH      (N_NODES * H)
#define NBLK_SCAN ((N_NODES + 255) / 256)   // 391

// two-level CSR build
#define TILE1   4096
#define NB1     391           // ceil(N/256): coarse buckets of 256 dst nodes
#define L2CAP   6144          // bucket edge cap (mean 4096, sigma 64 -> +32 sigma)

// ---------------------------------------------------------------- degree (int)
__global__ void deg_kernel(const int* __restrict__ dst, int* __restrict__ deg) {
    int e = blockIdx.x * blockDim.x + threadIdx.x;
    if (e < E_EDGES) atomicAdd(&deg[dst[e]], 1);
}

__global__ void dinv_kernel(const int* __restrict__ deg, float* __restrict__ dinv) {
    int n = blockIdx.x * blockDim.x + threadIdx.x;
    if (n < N_NODES) dinv[n] = rsqrtf((float)deg[n] + 1.0f);
}

// ---------------------------------------------------------------- scan (CSR rowptr)
__global__ void scan1_kernel(const int* __restrict__ deg, int* __restrict__ rowptr,
                             int* __restrict__ blockSums) {
    __shared__ int lds[256];
    int t = threadIdx.x;
    int i = blockIdx.x * 256 + t;
    int v = (i < N_NODES) ? deg[i] : 0;
    lds[t] = v;
    __syncthreads();
    for (int off = 1; off < 256; off <<= 1) {
        int add = (t >= off) ? lds[t - off] : 0;
        __syncthreads();
        lds[t] += add;
        __syncthreads();
    }
    if (i < N_NODES) rowptr[i] = lds[t] - v;
    if (t == 255) blockSums[blockIdx.x] = lds[255];
}

__global__ void scan2_kernel(const int* __restrict__ blockSums, int* __restrict__ blockOff) {
    __shared__ int lds[512];
    int t = threadIdx.x;
    int v = (t < NBLK_SCAN) ? blockSums[t] : 0;
    lds[t] = v;
    __syncthreads();
    for (int off = 1; off < 512; off <<= 1) {
        int add = (t >= off) ? lds[t - off] : 0;
        __syncthreads();
        lds[t] += add;
        __syncthreads();
    }
    if (t < NBLK_SCAN) blockOff[t] = lds[t] - v;
}

// finalize rowptr, emit rowptr[N]=E, init coarse-bucket cursors from rowptr.
__global__ void scan3_kernel(int* __restrict__ rowptr, const int* __restrict__ blockOff,
                             int* __restrict__ bcur) {
    int i = blockIdx.x * blockDim.x + threadIdx.x;
    if (i < N_NODES) {
        int r = rowptr[i] + blockOff[i >> 8];
        rowptr[i] = r;
        if ((i & 255) == 0) bcur[i >> 8] = r;
    } else if (i == N_NODES) {
        rowptr[N_NODES] = E_EDGES;
    }
}

// ---------------------------------------------------------------- L1: tile -> coarse buckets
__global__ __launch_bounds__(256) void l1sort_kernel(const int* __restrict__ src,
                                                     const int* __restrict__ dst,
                                                     int* __restrict__ bcur,
                                                     int* __restrict__ inter) {
    __shared__ int hist[NB1];
    __shared__ int sbase[NB1];
    __shared__ int gbase[NB1];
    __shared__ int scanA[512];
    __shared__ int scanB[512];
    __shared__ int ebuf[TILE1];
    __shared__ unsigned short bkt[TILE1];

    int tid   = threadIdx.x;
    int tbase = blockIdx.x * TILE1;
    int tcnt  = min(TILE1, E_EDGES - tbase);

    for (int i = tid; i < NB1; i += 256) hist[i] = 0;
    __syncthreads();

    int   pk[16];
    int   rk[16];
    short bb[16];
#pragma unroll
    for (int j = 0; j < 16; ++j) {
        int i = j * 256 + tid;
        if (i < tcnt) {
            int e = tbase + i;
            int s = src[e], d = dst[e];
            int b  = d >> 8;
            int dl = d & 255;
            pk[j] = s | (dl << 17);          // s:17 bits, d_local:8 bits
            bb[j] = (short)b;
            rk[j] = atomicAdd(&hist[b], 1);
        } else {
            pk[j] = -1; rk[j] = 0; bb[j] = 0;
        }
    }
    __syncthreads();

    for (int i = tid; i < 512; i += 256) scanA[i] = (i < NB1) ? hist[i] : 0;
    __syncthreads();
    int* A = scanA; int* B = scanB;
    for (int off = 1; off < 512; off <<= 1) {
        for (int i = tid; i < 512; i += 256)
            B[i] = A[i] + ((i >= off) ? A[i - off] : 0);
        __syncthreads();
        int* t = A; A = B; B = t;
    }
    for (int i = tid; i < NB1; i += 256) {
        int c = hist[i];
        sbase[i] = A[i] - c;                               // exclusive
        gbase[i] = (c > 0) ? atomicAdd(&bcur[i], c) : 0;   // grab global range
    }
    __syncthreads();

#pragma unroll
    for (int j = 0; j < 16; ++j) {
        if (pk[j] >= 0) {
            int b   = bb[j];
            int pos = sbase[b] + rk[j];
            ebuf[pos] = pk[j];
            bkt[pos]  = (unsigned short)b;
        }
    }
    __syncthreads();

    for (int i = tid; i < tcnt; i += 256) {
        int b = bkt[i];
        inter[gbase[b] + (i - sbase[b])] = ebuf[i];
    }
}

// ---------------------------------------------------------------- L2: bucket -> node-sorted edata
__global__ __launch_bounds__(256) void l2sort_kernel(const int* __restrict__ rowptr,
                                                     const int* __restrict__ inter,
                                                     const float* __restrict__ dinv,
                                                     float2* __restrict__ edata) {
    __shared__ int    nhist[256];
    __shared__ int    nscan[256];
    __shared__ float2 ebuf[L2CAP];

    int tid      = threadIdx.x;
    int b        = blockIdx.x;
    int nodeBase = b << 8;
    int lo       = rowptr[nodeBase];
    int hi       = rowptr[min(nodeBase + 256, N_NODES)];
    int cnt      = hi - lo;
    if (cnt > L2CAP) cnt = L2CAP;

    nhist[tid] = 0;
    __syncthreads();

    int vv[24];
    int dr[24];
#pragma unroll
    for (int j = 0; j < 24; ++j) {
        int i = j * 256 + tid;
        if (i < cnt) {
            int v  = inter[lo + i];
            int dl = (v >> 17) & 255;
            int r  = atomicAdd(&nhist[dl], 1);
            vv[j] = v;
            dr[j] = (dl << 16) | r;
        } else {
            vv[j] = -1; dr[j] = 0;
        }
    }
    __syncthreads();

    int vval = nhist[tid];
    nscan[tid] = vval;
    __syncthreads();
    for (int off = 1; off < 256; off <<= 1) {
        int add = (tid >= off) ? nscan[tid - off] : 0;
        __syncthreads();
        nscan[tid] += add;
        __syncthreads();
    }
    nhist[tid] = nscan[tid] - vval;   // exclusive base per node
    __syncthreads();

#pragma unroll
    for (int j = 0; j < 24; ++j) {
        if (vv[j] >= 0) {
            int dl  = dr[j] >> 16;
            int r   = dr[j] & 0xFFFF;
            int pos = nhist[dl] + r;
            int s   = vv[j] & 0x1FFFF;
            int d   = nodeBase + dl;
            ebuf[pos] = make_float2(__int_as_float(s), dinv[s] * dinv[d]);
        }
    }
    __syncthreads();

    for (int i = tid; i < cnt; i += 256)
        edata[lo + i] = ebuf[i];
}

// ---------------------------------------------------------------- layer-1: pad x to N x 16 (fp16)
__global__ void pad_kernel(const float* __restrict__ x, __half* __restrict__ xph) {
    int idx = blockIdx.x * blockDim.x + threadIdx.x;
    if (idx >= N_NODES * 16) return;
    int n = idx >> 4, c = idx & 15;
    xph[idx] = __float2half((c < F_IN) ? x[n * F_IN + c] : 0.0f);
}

// ---------------------------------------------------------------- layer-1 gather on fp16 x (16-wide)
__global__ __launch_bounds__(256) void gather16_kernel(const int* __restrict__ rowptr,
                                                       const float2* __restrict__ edata,
                                                       const __half* __restrict__ xph,
                                                       const float* __restrict__ dinv,
                                                       float* __restrict__ agg16) {
    int tid  = threadIdx.x;
    int n    = blockIdx.x * 4 + (tid >> 6);
    if (n >= N_NODES) return;
    int lane = tid & 63;
    int grp  = lane >> 2;          // 0..15
    int c4   = (lane & 3) * 4;     // half-index base: 0,4,8,12

    int start = rowptr[n], end = rowptr[n + 1];
    float4 acc = make_float4(0.f, 0.f, 0.f, 0.f);
    for (int p = start; p < end; p += 16) {
        int q = p + grp;
        float2 ed = (q < end) ? edata[q] : make_float2(__int_as_float(0), 0.0f);
        int   s = __float_as_int(ed.x);
        float w = ed.y;
        uint2 raw = *(const uint2*)&xph[s * 16 + c4];
        float2 f01 = __half22float2(*reinterpret_cast<__half2*>(&raw.x));
        float2 f23 = __half22float2(*reinterpret_cast<__half2*>(&raw.y));
        acc.x = fmaf(w, f01.x, acc.x);
        acc.y = fmaf(w, f01.y, acc.y);
        acc.z = fmaf(w, f23.x, acc.z);
        acc.w = fmaf(w, f23.y, acc.w);
    }
#pragma unroll
    for (int off = 4; off < 64; off <<= 1) {
        acc.x += __shfl_xor(acc.x, off);
        acc.y += __shfl_xor(acc.y, off);
        acc.z += __shfl_xor(acc.z, off);
        acc.w += __shfl_xor(acc.w, off);
    }
    if (grp == 0) {
        uint2 raw = *(const uint2*)&xph[n * 16 + c4];
        float2 s01 = __half22float2(*reinterpret_cast<__half2*>(&raw.x));
        float2 s23 = __half22float2(*reinterpret_cast<__half2*>(&raw.y));
        float  di   = dinv[n];
        float  di2  = di * di;
        acc.x = fmaf(s01.x, di2, acc.x);
        acc.y = fmaf(s01.y, di2, acc.y);
        acc.z = fmaf(s23.x, di2, acc.z);
        acc.w = fmaf(s23.y, di2, acc.w);
        *(float4*)&agg16[n * 16 + c4] = acc;
    }
}

// ---------------------------------------------------------------- layer-1 matmul + bias + BN + ReLU
__global__ __launch_bounds__(256) void matmul16_bn_kernel(const float* __restrict__ agg16,
                                                          const float* __restrict__ W,
                                                          const float* __restrict__ b,
                                                          const float* __restrict__ g,
                                                          const float* __restrict__ be,
                                                          const float* __restrict__ m,
                                                          const float* __restrict__ v,
                                                          float* __restrict__ hout) {
    __shared__ float rowLds[16 * 16];
    __shared__ float Wlds[F_IN * 68];
    int tid  = threadIdx.x;
    int base = blockIdx.x * 16;

    if (tid < 64) {
        int r = tid >> 2, c = (tid & 3) * 4;
        *(float4*)&rowLds[r * 16 + c] = *(const float4*)&agg16[(base + r) * 16 + c];
    }
    for (int i = tid; i < F_IN * 64; i += 256) {
        int k = i >> 6, c = i & 63;
        Wlds[k * 68 + c] = W[i];
    }
    __syncthreads();

    int r  = tid >> 4;
    int c4 = (tid & 15) * 4;
    float4 acc = make_float4(0.f, 0.f, 0.f, 0.f);
#pragma unroll
    for (int k = 0; k < F_IN; ++k) {
        float  rv = rowLds[r * 16 + k];
        float4 wv = *(const float4*)&Wlds[k * 68 + c4];
        acc.x = fmaf(rv, wv.x, acc.x);
        acc.y = fmaf(rv, wv.y, acc.y);
        acc.z = fmaf(rv, wv.z, acc.z);
        acc.w = fmaf(rv, wv.w, acc.w);
    }
    float4 gv = *(const float4*)&g[c4];
    float4 vv = *(const float4*)&v[c4];
    float4 bv = *(const float4*)&b[c4];
    float4 mv = *(const float4*)&m[c4];
    float4 bev= *(const float4*)&be[c4];
    float4 sc, sh, r2;
    sc.x = gv.x * rsqrtf(vv.x + BN_EPS);
    sc.y = gv.y * rsqrtf(vv.y + BN_EPS);
    sc.z = gv.z * rsqrtf(vv.z + BN_EPS);
    sc.w = gv.w * rsqrtf(vv.w + BN_EPS);
    sh.x = bev.x + (bv.x - mv.x) * sc.x;
    sh.y = bev.y + (bv.y - mv.y) * sc.y;
    sh.z = bev.z + (bv.z - mv.z) * sc.z;
    sh.w = bev.w + (bv.w - mv.w) * sc.w;
    r2.x = fmaxf(acc.x * sc.x + sh.x, 0.f);
    r2.y = fmaxf(acc.y * sc.y + sh.y, 0.f);
    r2.z = fmaxf(acc.z * sc.z + sh.z, 0.f);
    r2.w = fmaxf(acc.w * sc.w + sh.w, 0.f);
    *(float4*)&hout[(base + r) * H + c4] = r2;
}

// ---------------------------------------------------------------- dense h @ W (H=64) -> fp16 out
__global__ __launch_bounds__(256) void matmul_kernel(const float* __restrict__ hin,
                                                     const float* __restrict__ W,
                                                     __half* __restrict__ houth) {
    __shared__ float rowLds[16 * 65];
    __shared__ float Wlds[H * 68];
    int tid  = threadIdx.x;
    int base = blockIdx.x * 16;

    for (int i = tid; i < H * 64; i += 256)
        Wlds[(i >> 6) * 68 + (i & 63)] = W[i];
    for (int i = tid; i < 16 * H; i += 256) {
        int r = i >> 6, k = i & 63;
        rowLds[r * 65 + k] = hin[(base + r) * H + k];
    }
    __syncthreads();

    int r  = tid >> 4;
    int c4 = (tid & 15) * 4;
    float4 acc = make_float4(0.f, 0.f, 0.f, 0.f);
#pragma unroll
    for (int k = 0; k < H; ++k) {
        float  rv = rowLds[r * 65 + k];
        float4 wv = *(const float4*)&Wlds[k * 68 + c4];
        acc.x = fmaf(rv, wv.x, acc.x);
        acc.y = fmaf(rv, wv.y, acc.y);
        acc.z = fmaf(rv, wv.z, acc.z);
        acc.w = fmaf(rv, wv.w, acc.w);
    }
    __half2 h01 = __float22half2_rn(make_float2(acc.x, acc.y));
    __half2 h23 = __float22half2_rn(make_float2(acc.z, acc.w));
    uint2 packed;
    packed.x = *reinterpret_cast<unsigned*>(&h01);
    packed.y = *reinterpret_cast<unsigned*>(&h23);
    *(uint2*)&houth[(base + r) * H + c4] = packed;
}

// ---------------------------------------------------------------- CSR gather (fp16 rows) + self + BN + ReLU
__global__ __launch_bounds__(256) void gather_kernel(const int* __restrict__ rowptr,
                                                     const float2* __restrict__ edata,
                                                     const __half* __restrict__ hWh,
                                                     const float* __restrict__ dinv,
                                                     const float* __restrict__ b,
                                                     const float* __restrict__ g,
                                                     const float* __restrict__ be,
                                                     const float* __restrict__ m,
                                                     const float* __restrict__ v,
                                                     float* __restrict__ hout) {
    int tid  = threadIdx.x;
    int n    = blockIdx.x * 4 + (tid >> 6);
    if (n >= N_NODES) return;
    int lane = tid & 63;
    int grp  = lane >> 4;          // 0..3: edge slot within quad
    int c4   = (lane & 15) * 4;    // half-index base (4 cols/lane)

    int start = rowptr[n], end = rowptr[n + 1];
    float4 acc  = make_float4(0.f, 0.f, 0.f, 0.f);
    float4 acc2 = make_float4(0.f, 0.f, 0.f, 0.f);
    // 2-deep unroll: two independent edge-quads in flight
    for (int p = start; p < end; p += 8) {
        int q1 = p + grp;
        int q2 = p + 4 + grp;
        float2 e1 = (q1 < end) ? edata[q1] : make_float2(__int_as_float(0), 0.0f);
        float2 e2 = (q2 < end) ? edata[q2] : make_float2(__int_as_float(0), 0.0f);
        int   s1 = __float_as_int(e1.x); float w1 = e1.y;
        int   s2 = __float_as_int(e2.x); float w2 = e2.y;
        uint2 r1 = *(const uint2*)&hWh[s1 * H + c4];
        uint2 r2 = *(const uint2*)&hWh[s2 * H + c4];
        float2 a01 = __half22float2(*reinterpret_cast<__half2*>(&r1.x));
        float2 a23 = __half22float2(*reinterpret_cast<__half2*>(&r1.y));
        acc.x = fmaf(w1, a01.x, acc.x);
        acc.y = fmaf(w1, a01.y, acc.y);
        acc.z = fmaf(w1, a23.x, acc.z);
        acc.w = fmaf(w1, a23.y, acc.w);
        float2 b01 = __half22float2(*reinterpret_cast<__half2*>(&r2.x));
        float2 b23 = __half22float2(*reinterpret_cast<__half2*>(&r2.y));
        acc2.x = fmaf(w2, b01.x, acc2.x);
        acc2.y = fmaf(w2, b01.y, acc2.y);
        acc2.z = fmaf(w2, b23.x, acc2.z);
        acc2.w = fmaf(w2, b23.y, acc2.w);
    }
    acc.x += acc2.x; acc.y += acc2.y; acc.z += acc2.z; acc.w += acc2.w;
#pragma unroll
    for (int off = 16; off < 64; off <<= 1) {
        acc.x += __shfl_xor(acc.x, off);
        acc.y += __shfl_xor(acc.y, off);
        acc.z += __shfl_xor(acc.z, off);
        acc.w += __shfl_xor(acc.w, off);
    }
    if (grp == 0) {
        uint2 rs = *(const uint2*)&hWh[n * H + c4];
        float2 s01 = __half22float2(*reinterpret_cast<__half2*>(&rs.x));
        float2 s23 = __half22float2(*reinterpret_cast<__half2*>(&rs.y));
        float  di   = dinv[n];
        float  di2  = di * di;
        float4 gv = *(const float4*)&g[c4];
        float4 vv = *(const float4*)&v[c4];
        float4 bv = *(const float4*)&b[c4];
        float4 mv = *(const float4*)&m[c4];
        float4 bev= *(const float4*)&be[c4];
        float4 sc, sh, r2;
        sc.x = gv.x * rsqrtf(vv.x + BN_EPS);
        sc.y = gv.y * rsqrtf(vv.y + BN_EPS);
        sc.z = gv.z * rsqrtf(vv.z + BN_EPS);
        sc.w = gv.w * rsqrtf(vv.w + BN_EPS);
        sh.x = bev.x + (bv.x - mv.x) * sc.x;
        sh.y = bev.y + (bv.y - mv.y) * sc.y;
        sh.z = bev.z + (bv.z - mv.z) * sc.z;
        sh.w = bev.w + (bv.w - mv.w) * sc.w;
        r2.x = fmaxf((acc.x + s01.x * di2) * sc.x + sh.x, 0.f);
        r2.y = fmaxf((acc.y + s01.y * di2) * sc.y + sh.y, 0.f);
        r2.z = fmaxf((acc.z + s23.x * di2) * sc.z + sh.z, 0.f);
        r2.w = fmaxf((acc.w + s23.y * di2) * sc.w + sh.w, 0.f);
        *(float4*)&hout[n * H + c4] = r2;
    }
}

// ---------------------------------------------------------------- segmented mean pool
#define PCHUNK 128
__global__ void pool_kernel(const float* __restrict__ h, const int* __restrict__ batch,
                            float* __restrict__ pooled, float* __restrict__ counts) {
    int tid  = threadIdx.x;
    int wid  = blockIdx.x * 4 + (tid >> 6);
    int lane = tid & 63;
    int n0   = wid * PCHUNK;
    if (n0 >= N_NODES) return;
    int n1 = min(n0 + PCHUNK, N_NODES);

    int   curb = batch[n0];
    float acc  = 0.0f;
    int   run  = 0;
    for (int n = n0; n < n1; ++n) {
        int bb = batch[n];
        if (bb != curb) {
            atomicAdd(&pooled[curb * H + lane], acc);
            if (lane == 0) atomicAdd(&counts[curb], (float)run);
            acc = 0.0f; run = 0; curb = bb;
        }
        acc += h[n * H + lane];
        ++run;
    }
    atomicAdd(&pooled[curb * H + lane], acc);
    if (lane == 0) atomicAdd(&counts[curb], (float)run);
}

// ---------------------------------------------------------------- final MLP
__global__ void mlp_kernel(const float* __restrict__ pooled, const float* __restrict__ counts,
                           const float* __restrict__ fw1, const float* __restrict__ fb1,
                           const float* __restrict__ fw2, const float* __restrict__ fb2,
                           float* __restrict__ out) {
    __shared__ float prow[H];
    __shared__ float hid[H / 2];
    int b = blockIdx.x;
    int t = threadIdx.x;
    float cnt = fmaxf(counts[b], 1.0f);
    prow[t] = pooled[b * H + t] / cnt;
    __syncthreads();
    if (t < H / 2) {
        float acc = fb1[t];
#pragma unroll
        for (int k = 0; k < H; ++k) acc += prow[k] * fw1[k * (H / 2) + t];
        hid[t] = fmaxf(acc, 0.0f);
    }
    __syncthreads();
    if (t < C_CLS) {
        float acc = fb2[t];
#pragma unroll
        for (int j = 0; j < H / 2; ++j) acc += hid[j] * fw2[j * C_CLS + t];
        out[b * C_CLS + t] = acc;
    }
}

// ================================================================ launch
extern "C" void kernel_launch(void* const* d_in, const int* in_sizes, int n_in,
                              void* d_out, int out_size, void* d_ws, size_t ws_size,
                              hipStream_t stream) {
    const float* x          = (const float*)d_in[0];
    const int*   edge_index = (const int*)d_in[1];
    const int*   batch      = (const int*)d_in[2];

    const float* W1 = (const float*)d_in[3];
    const float* b1 = (const float*)d_in[4];
    const float* g1 = (const float*)d_in[5];
    const float* be1= (const float*)d_in[6];
    const float* m1 = (const float*)d_in[7];
    const float* v1 = (const float*)d_in[8];
    const float* W2 = (const float*)d_in[9];
    const float* b2 = (const float*)d_in[10];
    const float* g2 = (const float*)d_in[11];
    const float* be2= (const float*)d_in[12];
    const float* m2 = (const float*)d_in[13];
    const float* v2 = (const float*)d_in[14];
    const float* W3 = (const float*)d_in[15];
    const float* b3 = (const float*)d_in[16];
    const float* g3 = (const float*)d_in[17];
    const float* be3= (const float*)d_in[18];
    const float* m3 = (const float*)d_in[19];
    const float* v3 = (const float*)d_in[20];
    const float* fw1= (const float*)d_in[21];
    const float* fb1= (const float*)d_in[22];
    const float* fw2= (const float*)d_in[23];
    const float* fb2= (const float*)d_in[24];

    const int* src = edge_index;            // edge_index[0, :]
    const int* dst = edge_index + E_EDGES;  // edge_index[1, :]

    // ---------------- workspace carve-up (floats) ----------------
    float* ws      = (float*)d_ws;
    float* hW      = ws;                          // region: fp16 hWh / layer-1 xph+agg16+inter
    float* hbuf    = ws + (size_t)NH;             // NH fp32
    float2* edata  = (float2*)(ws + 2 * (size_t)NH);        // E float2
    float* fafter  = ws + 2 * (size_t)NH + 2 * (size_t)E_EDGES;
    int*   deg_i   = (int*)fafter;                // N
    float* dinv    = fafter + N_NODES;            // N
    int*   rowptr  = (int*)(fafter + 2 * N_NODES);// N+1
    int*   blockSums = (int*)(fafter + 3 * N_NODES + 1); // 512
    int*   blockOff  = blockSums + 512;           // 512
    int*   bcur      = blockOff + 512;            // 512 (NB1=391 used)
    float* pooled  = fafter + 3 * N_NODES + 1 + 1536;    // B*H
    float* counts  = pooled + B_GR * H;           // B

    __half* hWh  = (__half*)hW;                         // N*64 halves (12.8 MB)
    __half* xph  = (__half*)hW;                         // N*16 halves (layer-1 phase)
    float* agg16 = hW + (size_t)N_NODES * 16;           // N*16 fp32
    int*   inter = (int*)(hW + 2 * (size_t)N_NODES * 16); // E ints (dead before hWh written)

    float* out = (float*)d_out;

    // ---------------- degree / dinv / CSR build ----------------
    hipMemsetAsync(deg_i, 0, N_NODES * sizeof(int), stream);
    hipMemsetAsync(pooled, 0, (B_GR * H + B_GR) * sizeof(float), stream);

    deg_kernel<<<(E_EDGES + 255) / 256, 256, 0, stream>>>(dst, deg_i);
    dinv_kernel<<<(N_NODES + 255) / 256, 256, 0, stream>>>(deg_i, dinv);

    scan1_kernel<<<NBLK_SCAN, 256, 0, stream>>>(deg_i, rowptr, blockSums);
    scan2_kernel<<<1, 512, 0, stream>>>(blockSums, blockOff);
    scan3_kernel<<<(N_NODES + 256) / 256, 256, 0, stream>>>(rowptr, blockOff, bcur);

    l1sort_kernel<<<(E_EDGES + TILE1 - 1) / TILE1, 256, 0, stream>>>(src, dst, bcur, inter);
    l2sort_kernel<<<NB1, 256, 0, stream>>>(rowptr, inter, dinv, edata);

    const int mmGrid = N_NODES / 16;   // 6250
    const int gGrid  = N_NODES / 4;    // 25000

    // ---- layer 1: aggregate fp16 x (16-wide) then matmul+BN+ReLU
    pad_kernel<<<(N_NODES * 16 + 255) / 256, 256, 0, stream>>>(x, xph);
    gather16_kernel<<<gGrid, 256, 0, stream>>>(rowptr, edata, xph, dinv, agg16);
    matmul16_bn_kernel<<<mmGrid, 256, 0, stream>>>(agg16, W1, b1, g1, be1, m1, v1, hbuf);

    // ---- layer 2
    matmul_kernel<<<mmGrid, 256, 0, stream>>>(hbuf, W2, hWh);
    gather_kernel<<<gGrid, 256, 0, stream>>>(rowptr, edata, hWh, dinv, b2, g2, be2, m2, v2, hbuf);

    // ---- layer 3
    matmul_kernel<<<mmGrid, 256, 0, stream>>>(hbuf, W3, hWh);
    gather_kernel<<<gGrid, 256, 0, stream>>>(rowptr, edata, hWh, dinv, b3, g3, be3, m3, v3, hbuf);

    // ---- pool + MLP head
    const int poolWaves = (N_NODES + PCHUNK - 1) / PCHUNK;
    pool_kernel<<<(poolWaves + 3) / 4, 256, 0, stream>>>(hbuf, batch, pooled, counts);
    mlp_kernel<<<B_GR, 64, 0, stream>>>(pooled, counts, fw1, fb1, fw2, fb2, out);
}

// Round 12
// 456.825 us; speedup vs baseline: 4.5914x; 1.0924x over previous
//
#include <hip/hip_runtime.h>
#include <hip/hip_bf16.h>
#include <hip/hip_fp16.h>

#define N_NODES 100000
#define E_EDGES 1600000
#define F_IN    10
#define H       64
#define B_GR    128
#define C_CLS   3
#define BN_EPS  1e-5f
#define NH      (N_NODES * H)

// two-level CSR build
#define TILE1   4096
#define NB1     391           // ceil(N/256): coarse buckets of 256 dst nodes
#define L2CAP   6144          // bucket edge cap (mean 4096, sigma 64 -> +32 sigma)

// ---------------------------------------------------------------- bucket histogram (LDS, few atomics)
__global__ __launch_bounds__(256) void bhist_kernel(const int* __restrict__ dst,
                                                    int* __restrict__ bucketCnt) {
    __shared__ int hist[NB1];
    int tid   = threadIdx.x;
    int tbase = blockIdx.x * TILE1;
    int tcnt  = min(TILE1, E_EDGES - tbase);
    for (int i = tid; i < NB1; i += 256) hist[i] = 0;
    __syncthreads();
    for (int i = tid; i < tcnt; i += 256)
        atomicAdd(&hist[dst[tbase + i] >> 8], 1);
    __syncthreads();
    for (int i = tid; i < NB1; i += 256) {
        int c = hist[i];
        if (c) atomicAdd(&bucketCnt[i], c);
    }
}

// ---------------------------------------------------------------- bucket scan (1 block)
__global__ void bscan_kernel(const int* __restrict__ bucketCnt,
                             int* __restrict__ bucketBase, int* __restrict__ bcur) {
    __shared__ int lds[512];
    int t = threadIdx.x;
    int v = (t < NB1) ? bucketCnt[t] : 0;
    lds[t] = v;
    __syncthreads();
    for (int off = 1; off < 512; off <<= 1) {
        int add = (t >= off) ? lds[t - off] : 0;
        __syncthreads();
        lds[t] += add;
        __syncthreads();
    }
    if (t < NB1) {
        int base = lds[t] - v;     // exclusive
        bucketBase[t] = base;
        bcur[t] = base;
    }
    if (t == 0) bucketBase[NB1] = E_EDGES;
}

// ---------------------------------------------------------------- L1: tile -> coarse buckets
__global__ __launch_bounds__(256) void l1sort_kernel(const int* __restrict__ src,
                                                     const int* __restrict__ dst,
                                                     int* __restrict__ bcur,
                                                     int* __restrict__ inter) {
    __shared__ int hist[NB1];
    __shared__ int sbase[NB1];
    __shared__ int gbase[NB1];
    __shared__ int scanA[512];
    __shared__ int scanB[512];
    __shared__ int ebuf[TILE1];
    __shared__ unsigned short bkt[TILE1];

    int tid   = threadIdx.x;
    int tbase = blockIdx.x * TILE1;
    int tcnt  = min(TILE1, E_EDGES - tbase);

    for (int i = tid; i < NB1; i += 256) hist[i] = 0;
    __syncthreads();

    int   pk[16];
    int   rk[16];
    short bb[16];
#pragma unroll
    for (int j = 0; j < 16; ++j) {
        int i = j * 256 + tid;
        if (i < tcnt) {
            int e = tbase + i;
            int s = src[e], d = dst[e];
            int b  = d >> 8;
            int dl = d & 255;
            pk[j] = s | (dl << 17);          // s:17 bits, d_local:8 bits
            bb[j] = (short)b;
            rk[j] = atomicAdd(&hist[b], 1);
        } else {
            pk[j] = -1; rk[j] = 0; bb[j] = 0;
        }
    }
    __syncthreads();

    for (int i = tid; i < 512; i += 256) scanA[i] = (i < NB1) ? hist[i] : 0;
    __syncthreads();
    int* A = scanA; int* B = scanB;
    for (int off = 1; off < 512; off <<= 1) {
        for (int i = tid; i < 512; i += 256)
            B[i] = A[i] + ((i >= off) ? A[i - off] : 0);
        __syncthreads();
        int* t = A; A = B; B = t;
    }
    for (int i = tid; i < NB1; i += 256) {
        int c = hist[i];
        sbase[i] = A[i] - c;                               // exclusive
        gbase[i] = (c > 0) ? atomicAdd(&bcur[i], c) : 0;   // grab global range
    }
    __syncthreads();

#pragma unroll
    for (int j = 0; j < 16; ++j) {
        if (pk[j] >= 0) {
            int b   = bb[j];
            int pos = sbase[b] + rk[j];
            ebuf[pos] = pk[j];
            bkt[pos]  = (unsigned short)b;
        }
    }
    __syncthreads();

    for (int i = tid; i < tcnt; i += 256) {
        int b = bkt[i];
        inter[gbase[b] + (i - sbase[b])] = ebuf[i];
    }
}

// ---------------------------------------------------------------- L2: bucket -> node-sorted esrc + dinv + rowptr
__global__ __launch_bounds__(256) void l2sort_kernel(const int* __restrict__ bucketBase,
                                                     const int* __restrict__ inter,
                                                     float* __restrict__ dinv,
                                                     int* __restrict__ rowptr,
                                                     int* __restrict__ esrc) {
    __shared__ int nhist[256];
    __shared__ int nbase[256];
    __shared__ int ebuf[L2CAP];

    int tid      = threadIdx.x;
    int b        = blockIdx.x;
    int nodeBase = b << 8;
    int lo       = bucketBase[b];
    int hi       = bucketBase[b + 1];
    int cnt      = hi - lo;
    if (cnt > L2CAP) cnt = L2CAP;

    nhist[tid] = 0;
    __syncthreads();

    int vv[24];
    int dr[24];
#pragma unroll
    for (int j = 0; j < 24; ++j) {
        int i = j * 256 + tid;
        if (i < cnt) {
            int v  = inter[lo + i];
            int dl = (v >> 17) & 255;
            int r  = atomicAdd(&nhist[dl], 1);
            vv[j] = v;
            dr[j] = (dl << 16) | r;
        } else {
            vv[j] = -1; dr[j] = 0;
        }
    }
    __syncthreads();

    int deg = nhist[tid];
    // inclusive scan of per-node counts (then derive exclusive)
    nbase[tid] = deg;
    __syncthreads();
    for (int off = 1; off < 256; off <<= 1) {
        int add = (tid >= off) ? nbase[tid - off] : 0;
        __syncthreads();
        nbase[tid] += add;
        __syncthreads();
    }
    int ex = nbase[tid] - deg;   // exclusive base within bucket

    int node = nodeBase + tid;
    if (node < N_NODES) {
        dinv[node]   = rsqrtf((float)deg + 1.0f);
        rowptr[node] = lo + ex;
    }
    if (b == NB1 - 1 && tid == 0) rowptr[N_NODES] = E_EDGES;

    nbase[tid] = ex;             // own-slot rewrite (no cross-thread read before next barrier)
    __syncthreads();

#pragma unroll
    for (int j = 0; j < 24; ++j) {
        if (vv[j] >= 0) {
            int dl  = dr[j] >> 16;
            int r   = dr[j] & 0xFFFF;
            ebuf[nbase[dl] + r] = vv[j] & 0x1FFFF;   // src id
        }
    }
    __syncthreads();

    for (int i = tid; i < cnt; i += 256)
        esrc[lo + i] = ebuf[i];
}

// ---------------------------------------------------------------- layer-1: pad x to N x 16 (fp16)
__global__ void pad_kernel(const float* __restrict__ x, __half* __restrict__ xph) {
    int idx = blockIdx.x * blockDim.x + threadIdx.x;
    if (idx >= N_NODES * 16) return;
    int n = idx >> 4, c = idx & 15;
    xph[idx] = __float2half((c < F_IN) ? x[n * F_IN + c] : 0.0f);
}

// ---------------------------------------------------------------- layer-1 gather on fp16 x (16-wide)
__global__ __launch_bounds__(256) void gather16_kernel(const int* __restrict__ rowptr,
                                                       const int* __restrict__ esrc,
                                                       const __half* __restrict__ xph,
                                                       const float* __restrict__ dinv,
                                                       float* __restrict__ agg16) {
    int tid  = threadIdx.x;
    int n    = blockIdx.x * 4 + (tid >> 6);
    if (n >= N_NODES) return;
    int lane = tid & 63;
    int grp  = lane >> 2;          // 0..15
    int c4   = (lane & 3) * 4;     // half-index base: 0,4,8,12

    int start = rowptr[n], end = rowptr[n + 1];
    float dn  = dinv[n];
    float4 acc = make_float4(0.f, 0.f, 0.f, 0.f);
    for (int p = start; p < end; p += 16) {
        int q = p + grp;
        int   s = (q < end) ? esrc[q] : 0;
        float w = ((q < end) ? dinv[s] : 0.0f) * dn;
        uint2 raw = *(const uint2*)&xph[s * 16 + c4];
        float2 f01 = __half22float2(*reinterpret_cast<__half2*>(&raw.x));
        float2 f23 = __half22float2(*reinterpret_cast<__half2*>(&raw.y));
        acc.x = fmaf(w, f01.x, acc.x);
        acc.y = fmaf(w, f01.y, acc.y);
        acc.z = fmaf(w, f23.x, acc.z);
        acc.w = fmaf(w, f23.y, acc.w);
    }
#pragma unroll
    for (int off = 4; off < 64; off <<= 1) {
        acc.x += __shfl_xor(acc.x, off);
        acc.y += __shfl_xor(acc.y, off);
        acc.z += __shfl_xor(acc.z, off);
        acc.w += __shfl_xor(acc.w, off);
    }
    if (grp == 0) {
        uint2 raw = *(const uint2*)&xph[n * 16 + c4];
        float2 s01 = __half22float2(*reinterpret_cast<__half2*>(&raw.x));
        float2 s23 = __half22float2(*reinterpret_cast<__half2*>(&raw.y));
        float  di2  = dn * dn;
        acc.x = fmaf(s01.x, di2, acc.x);
        acc.y = fmaf(s01.y, di2, acc.y);
        acc.z = fmaf(s23.x, di2, acc.z);
        acc.w = fmaf(s23.y, di2, acc.w);
        *(float4*)&agg16[n * 16 + c4] = acc;
    }
}

// ---------------------------------------------------------------- layer-1 matmul + bias + BN + ReLU
__global__ __launch_bounds__(256) void matmul16_bn_kernel(const float* __restrict__ agg16,
                                                          const float* __restrict__ W,
                                                          const float* __restrict__ b,
                                                          const float* __restrict__ g,
                                                          const float* __restrict__ be,
                                                          const float* __restrict__ m,
                                                          const float* __restrict__ v,
                                                          float* __restrict__ hout) {
    __shared__ float rowLds[16 * 16];
    __shared__ float Wlds[F_IN * 68];
    int tid  = threadIdx.x;
    int base = blockIdx.x * 16;

    if (tid < 64) {
        int r = tid >> 2, c = (tid & 3) * 4;
        *(float4*)&rowLds[r * 16 + c] = *(const float4*)&agg16[(base + r) * 16 + c];
    }
    for (int i = tid; i < F_IN * 64; i += 256) {
        int k = i >> 6, c = i & 63;
        Wlds[k * 68 + c] = W[i];
    }
    __syncthreads();

    int r  = tid >> 4;
    int c4 = (tid & 15) * 4;
    float4 acc = make_float4(0.f, 0.f, 0.f, 0.f);
#pragma unroll
    for (int k = 0; k < F_IN; ++k) {
        float  rv = rowLds[r * 16 + k];
        float4 wv = *(const float4*)&Wlds[k * 68 + c4];
        acc.x = fmaf(rv, wv.x, acc.x);
        acc.y = fmaf(rv, wv.y, acc.y);
        acc.z = fmaf(rv, wv.z, acc.z);
        acc.w = fmaf(rv, wv.w, acc.w);
    }
    float4 gv = *(const float4*)&g[c4];
    float4 vv = *(const float4*)&v[c4];
    float4 bv = *(const float4*)&b[c4];
    float4 mv = *(const float4*)&m[c4];
    float4 bev= *(const float4*)&be[c4];
    float4 sc, sh, r2;
    sc.x = gv.x * rsqrtf(vv.x + BN_EPS);
    sc.y = gv.y * rsqrtf(vv.y + BN_EPS);
    sc.z = gv.z * rsqrtf(vv.z + BN_EPS);
    sc.w = gv.w * rsqrtf(vv.w + BN_EPS);
    sh.x = bev.x + (bv.x - mv.x) * sc.x;
    sh.y = bev.y + (bv.y - mv.y) * sc.y;
    sh.z = bev.z + (bv.z - mv.z) * sc.z;
    sh.w = bev.w + (bv.w - mv.w) * sc.w;
    r2.x = fmaxf(acc.x * sc.x + sh.x, 0.f);
    r2.y = fmaxf(acc.y * sc.y + sh.y, 0.f);
    r2.z = fmaxf(acc.z * sc.z + sh.z, 0.f);
    r2.w = fmaxf(acc.w * sc.w + sh.w, 0.f);
    *(float4*)&hout[(base + r) * H + c4] = r2;
}

// ---------------------------------------------------------------- dense h @ W (H=64) -> fp16 out
__global__ __launch_bounds__(256) void matmul_kernel(const float* __restrict__ hin,
                                                     const float* __restrict__ W,
                                                     __half* __restrict__ houth) {
    __shared__ float rowLds[16 * 65];
    __shared__ float Wlds[H * 68];
    int tid  = threadIdx.x;
    int base = blockIdx.x * 16;

    for (int i = tid; i < H * 64; i += 256)
        Wlds[(i >> 6) * 68 + (i & 63)] = W[i];
    for (int i = tid; i < 16 * H; i += 256) {
        int r = i >> 6, k = i & 63;
        rowLds[r * 65 + k] = hin[(base + r) * H + k];
    }
    __syncthreads();

    int r  = tid >> 4;
    int c4 = (tid & 15) * 4;
    float4 acc = make_float4(0.f, 0.f, 0.f, 0.f);
#pragma unroll
    for (int k = 0; k < H; ++k) {
        float  rv = rowLds[r * 65 + k];
        float4 wv = *(const float4*)&Wlds[k * 68 + c4];
        acc.x = fmaf(rv, wv.x, acc.x);
        acc.y = fmaf(rv, wv.y, acc.y);
        acc.z = fmaf(rv, wv.z, acc.z);
        acc.w = fmaf(rv, wv.w, acc.w);
    }
    __half2 h01 = __float22half2_rn(make_float2(acc.x, acc.y));
    __half2 h23 = __float22half2_rn(make_float2(acc.z, acc.w));
    uint2 packed;
    packed.x = *reinterpret_cast<unsigned*>(&h01);
    packed.y = *reinterpret_cast<unsigned*>(&h23);
    *(uint2*)&houth[(base + r) * H + c4] = packed;
}

// ---------------------------------------------------------------- CSR gather (fp16 rows) + self + BN + ReLU
__global__ __launch_bounds__(256) void gather_kernel(const int* __restrict__ rowptr,
                                                     const int* __restrict__ esrc,
                                                     const __half* __restrict__ hWh,
                                                     const float* __restrict__ dinv,
                                                     const float* __restrict__ b,
                                                     const float* __restrict__ g,
                                                     const float* __restrict__ be,
                                                     const float* __restrict__ m,
                                                     const float* __restrict__ v,
                                                     float* __restrict__ hout) {
    int tid  = threadIdx.x;
    int n    = blockIdx.x * 4 + (tid >> 6);
    if (n >= N_NODES) return;
    int lane = tid & 63;
    int grp  = lane >> 4;          // 0..3: edge slot within quad
    int c4   = (lane & 15) * 4;    // half-index base (4 cols/lane)

    int start = rowptr[n], end = rowptr[n + 1];
    float dn  = dinv[n];
    float4 acc  = make_float4(0.f, 0.f, 0.f, 0.f);
    float4 acc2 = make_float4(0.f, 0.f, 0.f, 0.f);
    for (int p = start; p < end; p += 8) {
        int q1 = p + grp;
        int q2 = p + 4 + grp;
        int   s1 = (q1 < end) ? esrc[q1] : 0;
        int   s2 = (q2 < end) ? esrc[q2] : 0;
        float w1 = ((q1 < end) ? dinv[s1] : 0.0f) * dn;
        float w2 = ((q2 < end) ? dinv[s2] : 0.0f) * dn;
        uint2 r1 = *(const uint2*)&hWh[s1 * H + c4];
        uint2 r2 = *(const uint2*)&hWh[s2 * H + c4];
        float2 a01 = __half22float2(*reinterpret_cast<__half2*>(&r1.x));
        float2 a23 = __half22float2(*reinterpret_cast<__half2*>(&r1.y));
        acc.x = fmaf(w1, a01.x, acc.x);
        acc.y = fmaf(w1, a01.y, acc.y);
        acc.z = fmaf(w1, a23.x, acc.z);
        acc.w = fmaf(w1, a23.y, acc.w);
        float2 b01 = __half22float2(*reinterpret_cast<__half2*>(&r2.x));
        float2 b23 = __half22float2(*reinterpret_cast<__half2*>(&r2.y));
        acc2.x = fmaf(w2, b01.x, acc2.x);
        acc2.y = fmaf(w2, b01.y, acc2.y);
        acc2.z = fmaf(w2, b23.x, acc2.z);
        acc2.w = fmaf(w2, b23.y, acc2.w);
    }
    acc.x += acc2.x; acc.y += acc2.y; acc.z += acc2.z; acc.w += acc2.w;
#pragma unroll
    for (int off = 16; off < 64; off <<= 1) {
        acc.x += __shfl_xor(acc.x, off);
        acc.y += __shfl_xor(acc.y, off);
        acc.z += __shfl_xor(acc.z, off);
        acc.w += __shfl_xor(acc.w, off);
    }
    if (grp == 0) {
        uint2 rs = *(const uint2*)&hWh[n * H + c4];
        float2 s01 = __half22float2(*reinterpret_cast<__half2*>(&rs.x));
        float2 s23 = __half22float2(*reinterpret_cast<__half2*>(&rs.y));
        float  di2  = dn * dn;
        float4 gv = *(const float4*)&g[c4];
        float4 vv = *(const float4*)&v[c4];
        float4 bv = *(const float4*)&b[c4];
        float4 mv = *(const float4*)&m[c4];
        float4 bev= *(const float4*)&be[c4];
        float4 sc, sh, r2;
        sc.x = gv.x * rsqrtf(vv.x + BN_EPS);
        sc.y = gv.y * rsqrtf(vv.y + BN_EPS);
        sc.z = gv.z * rsqrtf(vv.z + BN_EPS);
        sc.w = gv.w * rsqrtf(vv.w + BN_EPS);
        sh.x = bev.x + (bv.x - mv.x) * sc.x;
        sh.y = bev.y + (bv.y - mv.y) * sc.y;
        sh.z = bev.z + (bv.z - mv.z) * sc.z;
        sh.w = bev.w + (bv.w - mv.w) * sc.w;
        r2.x = fmaxf((acc.x + s01.x * di2) * sc.x + sh.x, 0.f);
        r2.y = fmaxf((acc.y + s01.y * di2) * sc.y + sh.y, 0.f);
        r2.z = fmaxf((acc.z + s23.x * di2) * sc.z + sh.z, 0.f);
        r2.w = fmaxf((acc.w + s23.y * di2) * sc.w + sh.w, 0.f);
        *(float4*)&hout[n * H + c4] = r2;
    }
}

// ---------------------------------------------------------------- segmented mean pool
#define PCHUNK 128
__global__ void pool_kernel(const float* __restrict__ h, const int* __restrict__ batch,
                            float* __restrict__ pooled, float* __restrict__ counts) {
    int tid  = threadIdx.x;
    int wid  = blockIdx.x * 4 + (tid >> 6);
    int lane = tid & 63;
    int n0   = wid * PCHUNK;
    if (n0 >= N_NODES) return;
    int n1 = min(n0 + PCHUNK, N_NODES);

    int   curb = batch[n0];
    float acc  = 0.0f;
    int   run  = 0;
    for (int n = n0; n < n1; ++n) {
        int bb = batch[n];
        if (bb != curb) {
            atomicAdd(&pooled[curb * H + lane], acc);
            if (lane == 0) atomicAdd(&counts[curb], (float)run);
            acc = 0.0f; run = 0; curb = bb;
        }
        acc += h[n * H + lane];
        ++run;
    }
    atomicAdd(&pooled[curb * H + lane], acc);
    if (lane == 0) atomicAdd(&counts[curb], (float)run);
}

// ---------------------------------------------------------------- final MLP
__global__ void mlp_kernel(const float* __restrict__ pooled, const float* __restrict__ counts,
                           const float* __restrict__ fw1, const float* __restrict__ fb1,
                           const float* __restrict__ fw2, const float* __restrict__ fb2,
                           float* __restrict__ out) {
    __shared__ float prow[H];
    __shared__ float hid[H / 2];
    int b = blockIdx.x;
    int t = threadIdx.x;
    float cnt = fmaxf(counts[b], 1.0f);
    prow[t] = pooled[b * H + t] / cnt;
    __syncthreads();
    if (t < H / 2) {
        float acc = fb1[t];
#pragma unroll
        for (int k = 0; k < H; ++k) acc += prow[k] * fw1[k * (H / 2) + t];
        hid[t] = fmaxf(acc, 0.0f);
    }
    __syncthreads();
    if (t < C_CLS) {
        float acc = fb2[t];
#pragma unroll
        for (int j = 0; j < H / 2; ++j) acc += hid[j] * fw2[j * C_CLS + t];
        out[b * C_CLS + t] = acc;
    }
}

// ================================================================ launch
extern "C" void kernel_launch(void* const* d_in, const int* in_sizes, int n_in,
                              void* d_out, int out_size, void* d_ws, size_t ws_size,
                              hipStream_t stream) {
    const float* x          = (const float*)d_in[0];
    const int*   edge_index = (const int*)d_in[1];
    const int*   batch      = (const int*)d_in[2];

    const float* W1 = (const float*)d_in[3];
    const float* b1 = (const float*)d_in[4];
    const float* g1 = (const float*)d_in[5];
    const float* be1= (const float*)d_in[6];
    const float* m1 = (const float*)d_in[7];
    const float* v1 = (const float*)d_in[8];
    const float* W2 = (const float*)d_in[9];
    const float* b2 = (const float*)d_in[10];
    const float* g2 = (const float*)d_in[11];
    const float* be2= (const float*)d_in[12];
    const float* m2 = (const float*)d_in[13];
    const float* v2 = (const float*)d_in[14];
    const float* W3 = (const float*)d_in[15];
    const float* b3 = (const float*)d_in[16];
    const float* g3 = (const float*)d_in[17];
    const float* be3= (const float*)d_in[18];
    const float* m3 = (const float*)d_in[19];
    const float* v3 = (const float*)d_in[20];
    const float* fw1= (const float*)d_in[21];
    const float* fb1= (const float*)d_in[22];
    const float* fw2= (const float*)d_in[23];
    const float* fb2= (const float*)d_in[24];

    const int* src = edge_index;            // edge_index[0, :]
    const int* dst = edge_index + E_EDGES;  // edge_index[1, :]

    // ---------------- workspace carve-up (floats) ----------------
    float* ws      = (float*)d_ws;
    float* hW      = ws;                          // region: fp16 hWh / layer-1 xph+agg16+inter
    float* hbuf    = ws + (size_t)NH;             // NH fp32
    int*   esrc    = (int*)(ws + 2 * (size_t)NH); // E ints
    float* fafter  = ws + 2 * (size_t)NH + (size_t)E_EDGES;
    float* dinv    = fafter;                      // N
    int*   rowptr  = (int*)(fafter + N_NODES);    // N+1
    int*   bucketCnt  = (int*)(fafter + 2 * N_NODES + 1); // 512
    int*   bucketBase = bucketCnt + 512;          // 512 (NB1+1 used)
    int*   bcur       = bucketBase + 512;         // 512
    float* pooled  = fafter + 2 * N_NODES + 1 + 1536;     // B*H
    float* counts  = pooled + B_GR * H;           // B

    __half* hWh  = (__half*)hW;                         // N*64 halves (12.8 MB)
    __half* xph  = (__half*)hW;                         // N*16 halves (layer-1 phase)
    float* agg16 = hW + (size_t)N_NODES * 16;           // N*16 fp32
    int*   inter = (int*)(hW + 2 * (size_t)N_NODES * 16); // E ints (dead before hWh written)

    float* out = (float*)d_out;

    // ---------------- CSR build (no N-wide atomics/scans) ----------------
    hipMemsetAsync(bucketCnt, 0, 512 * sizeof(int), stream);
    hipMemsetAsync(pooled, 0, (B_GR * H + B_GR) * sizeof(float), stream);

    const int nTiles = (E_EDGES + TILE1 - 1) / TILE1;   // 391
    bhist_kernel<<<nTiles, 256, 0, stream>>>(dst, bucketCnt);
    bscan_kernel<<<1, 512, 0, stream>>>(bucketCnt, bucketBase, bcur);
    l1sort_kernel<<<nTiles, 256, 0, stream>>>(src, dst, bcur, inter);
    l2sort_kernel<<<NB1, 256, 0, stream>>>(bucketBase, inter, dinv, rowptr, esrc);

    const int mmGrid = N_NODES / 16;   // 6250
    const int gGrid  = N_NODES / 4;    // 25000

    // ---- layer 1: aggregate fp16 x (16-wide) then matmul+BN+ReLU
    pad_kernel<<<(N_NODES * 16 + 255) / 256, 256, 0, stream>>>(x, xph);
    gather16_kernel<<<gGrid, 256, 0, stream>>>(rowptr, esrc, xph, dinv, agg16);
    matmul16_bn_kernel<<<mmGrid, 256, 0, stream>>>(agg16, W1, b1, g1, be1, m1, v1, hbuf);

    // ---- layer 2
    matmul_kernel<<<mmGrid, 256, 0, stream>>>(hbuf, W2, hWh);
    gather_kernel<<<gGrid, 256, 0, stream>>>(rowptr, esrc, hWh, dinv, b2, g2, be2, m2, v2, hbuf);

    // ---- layer 3
    matmul_kernel<<<mmGrid, 256, 0, stream>>>(hbuf, W3, hWh);
    gather_kernel<<<gGrid, 256, 0, stream>>>(rowptr, esrc, hWh, dinv, b3, g3, be3, m3, v3, hbuf);

    // ---- pool + MLP head
    const int poolWaves = (N_NODES + PCHUNK - 1) / PCHUNK;
    pool_kernel<<<(poolWaves + 3) / 4, 256, 0, stream>>>(hbuf, batch, pooled, counts);
    mlp_kernel<<<B_GR, 64, 0, stream>>>(pooled, counts, fw1, fb1, fw2, fb2, out);
}